// Round 14
// baseline (979.518 us; speedup 1.0000x reference)
//
#include <hip/hip_runtime.h>
#include <hip/hip_bf16.h>

// ---------------------------------------------------------------------------
// GAT (3 layers) + global mean pool + linear head.
// R14: tail compression — scan folded into deg_prep (last-block ticket),
// 2-bin scatter in mega0, pool fused into agg_h1 via atomics. agg8 at its
// measured ~3.8 TB/s random-gather floor (R7-R13 invariant).
// ---------------------------------------------------------------------------

#define LRELU(x) ((x) >= 0.f ? (x) : 0.2f * (x))

typedef unsigned short ushort8 __attribute__((ext_vector_type(8)));
typedef unsigned short ushort4v __attribute__((ext_vector_type(4)));
typedef __attribute__((ext_vector_type(8))) short bf16x8;
typedef __attribute__((ext_vector_type(4))) float f32x4;

__device__ __forceinline__ float bf2f(unsigned short u) {
    return __uint_as_float(((unsigned)u) << 16);
}
__device__ __forceinline__ unsigned short f2bf(float f) {
    __hip_bfloat16 b = __float2bfloat16(f);
    return *reinterpret_cast<unsigned short*>(&b);
}
__device__ __forceinline__ void gl_lds16(const unsigned short* g, unsigned short* l) {
    __builtin_amdgcn_global_load_lds((const __attribute__((address_space(1))) void*)g,
                                     (__attribute__((address_space(3))) void*)l, 16, 0, 0);
}

// ---------------- GEMM core ----------------
// C[M,Nn](bf16) = A[M,K](bf16) @ B[K,Nn], B transposed [Nn][K] bf16.
// Epilogue fuses attention logits (als/ald) via 16-lane shfl reduce.
// D layout: row = (lane>>4)*4 + reg, col = lane&15 (m89-verified, R5+ passed).

template <int BM, int BN, int WM, int WN, int H>
__device__ __forceinline__
void gemm_core(unsigned short* __restrict__ Ab, unsigned short* __restrict__ Bb,
               const unsigned short* __restrict__ A, const unsigned short* __restrict__ Bt,
               unsigned short* __restrict__ Cc,
               const float* __restrict__ a_src, const float* __restrict__ a_dst,
               float* __restrict__ als, float* __restrict__ ald,
               int M, int Nn, int K, int bxi, int byi) {
    constexpr int BK = 64;
    constexpr int MT = WM / 16, NT = WN / 16;
    constexpr int NWX = BN / WN;
    constexpr int NHL = WN / 32;
    const int tid = threadIdx.x;
    const int lane = tid & 63;
    const int wave = tid >> 6;
    const int wx = wave % NWX, wy = wave / NWX;
    const int by = byi * BM;
    const int bx = bxi * BN;
    const int r16 = lane & 15, kg = lane >> 4;
    const int srow = lane >> 3, sslot = lane & 7;

    f32x4 acc[MT][NT];
#pragma unroll
    for (int i = 0; i < MT; i++)
#pragma unroll
        for (int j = 0; j < NT; j++) acc[i][j] = (f32x4){0.f, 0.f, 0.f, 0.f};

    for (int k0 = 0; k0 < K; k0 += BK) {
        for (int t = wave; t < BM / 8; t += 4) {
            int gm = by + t * 8 + srow;
            if (gm >= M) gm = M - 1;              // clamp: garbage lands in unstored rows
            gl_lds16(A + (size_t)gm * K + k0 + sslot * 8, Ab + (t * 8) * BK);
        }
        for (int t = wave; t < BN / 8; t += 4) {
            int gn = bx + t * 8 + srow;
            gl_lds16(Bt + (size_t)gn * K + k0 + sslot * 8, Bb + (t * 8) * BK);
        }
        __syncthreads();
#pragma unroll
        for (int ks = 0; ks < 2; ks++) {
            bf16x8 bh[NT];
#pragma unroll
            for (int j = 0; j < NT; j++)
                bh[j] = *(const bf16x8*)(Bb + (wx * WN + j * 16 + r16) * BK + ks * 32 + kg * 8);
#pragma unroll
            for (int i = 0; i < MT; i++) {
                bf16x8 ah = *(const bf16x8*)(Ab + (wy * WM + i * 16 + r16) * BK + ks * 32 + kg * 8);
#pragma unroll
                for (int j = 0; j < NT; j++)
                    acc[i][j] = __builtin_amdgcn_mfma_f32_16x16x32_bf16(ah, bh[j], acc[i][j], 0, 0, 0);
            }
        }
        __syncthreads();
    }

    const int c0 = bx + wx * WN;
#pragma unroll
    for (int i = 0; i < MT; i++) {
#pragma unroll
        for (int r = 0; r < 4; r++) {
            int gm = by + wy * WM + i * 16 + kg * 4 + r;
            bool ok = gm < M;
            float sa[NHL] = {};
            float sd[NHL] = {};
#pragma unroll
            for (int j = 0; j < NT; j++) {
                int gn = c0 + j * 16 + r16;
                float v = acc[i][j][r];
                if (ok) Cc[(size_t)gm * Nn + gn] = f2bf(v);
                sa[j >> 1] += v * a_src[gn];
                sd[j >> 1] += v * a_dst[gn];
            }
#pragma unroll
            for (int m = 1; m < 16; m <<= 1) {
#pragma unroll
                for (int t = 0; t < NHL; t++) {
                    sa[t] += __shfl_xor(sa[t], m);
                    sd[t] += __shfl_xor(sd[t], m);
                }
            }
            if (ok && r16 == 0) {
#pragma unroll
                for (int t = 0; t < NHL; t++) {
                    int hh = (c0 >> 5) + t;
                    als[(size_t)gm * H + hh] = sa[t];
                    ald[(size_t)gm * H + hh] = sd[t];
                }
            }
        }
    }
}

// ---------------- deg ∥ prep, + last-block scan/gstart ----------------
// DEG blocks histogram; each fences + tickets. The LAST deg block runs the
// 256-thread rowptr scan + gstart searches in-kernel (deg updates are
// device-scope atomics -> coherent reads). PREP blocks are independent.

__global__ __launch_bounds__(256)
void deg_prep_scan(const int* __restrict__ dst, int* __restrict__ deg, int E, int N,
                   const float* __restrict__ x, const float* __restrict__ W0,
                   const float* __restrict__ W1, const float* __restrict__ W2,
                   unsigned short* __restrict__ xb, unsigned short* __restrict__ w0t,
                   unsigned short* __restrict__ w1t, unsigned short* __restrict__ w2t,
                   int DEG_BLKS, int* __restrict__ done,
                   int* __restrict__ rowptr, const int* __restrict__ batch,
                   int* __restrict__ gstart, int G) {
    const int tid = threadIdx.x;
    if ((int)blockIdx.x < DEG_BLKS) {
        int i = blockIdx.x * 256 + tid;
        if (i < E) atomicAdd(&deg[dst[i]], 1);
        else if (i < E + N) atomicAdd(&deg[i - E], 1);   // self loop
        __shared__ int islast;
        __threadfence();
        __syncthreads();
        if (tid == 0) islast = (atomicAdd(done, 1) == DEG_BLKS - 1);
        __syncthreads();
        if (!islast) return;
        __threadfence();
        // ---- scan (256 threads) + gstart ----
        for (int g = tid; g <= G; g += 256) {
            int lo = 0, hi = N;
            while (lo < hi) { int mid = (lo + hi) >> 1; if (batch[mid] < g) lo = mid + 1; else hi = mid; }
            gstart[g] = lo;
        }
        __shared__ int partial[256];
        const int chunk = (N + 255) / 256;
        const int start = min(tid * chunk, N);
        const int end = min(start + chunk, N);
        int s = 0;
        for (int i2 = start; i2 < end; i2++) s += deg[i2];
        partial[tid] = s;
        __syncthreads();
        for (int o = 1; o < 256; o <<= 1) {
            int v = (tid >= o) ? partial[tid - o] : 0;
            __syncthreads();
            partial[tid] += v;
            __syncthreads();
        }
        int run = (tid == 0) ? 0 : partial[tid - 1];
        for (int i2 = start; i2 < end; i2++) { rowptr[i2] = run; run += deg[i2]; }
        if (tid == 0) rowptr[N] = partial[255];
        return;
    }
    int i = (blockIdx.x - DEG_BLKS) * 256 + tid;
    int nx = N * 128;
    if (i < nx) { xb[i] = f2bf(x[i]); return; }
    i -= nx;
    if (i < 256 * 128) {                          // W0 [128][256] -> w0t [256][128]
        int n = i / 128, k = i - n * 128;
        w0t[i] = f2bf(W0[(size_t)k * 256 + n]);
        return;
    }
    i -= 256 * 128;
    if (i < 256 * 256) {                          // W1 [256][256] -> w1t [256][256]
        int n = i / 256, k = i - n * 256;
        w1t[i] = f2bf(W1[(size_t)k * 256 + n]);
        return;
    }
    i -= 256 * 256;
    if (i < 32 * 256) {                           // W2 [256][32] -> w2t [32][256]
        int n = i / 256, k = i - n * 256;
        w2t[i] = f2bf(W2[(size_t)k * 32 + n]);
    }
}

// ---------------- mega0: gemm0(+al) ∥ 2-bin scatter ----------------
// Bins write disjoint dst ranges -> order-independent. After both bins:
// rowptr[n] = END of segment n (shifted convention).

__global__ __launch_bounds__(256)
void mega0_kernel(const unsigned short* __restrict__ A, const unsigned short* __restrict__ Bt,
                  unsigned short* __restrict__ Cc,
                  const float* __restrict__ a_src, const float* __restrict__ a_dst,
                  float* __restrict__ als, float* __restrict__ ald, int M, int K,
                  const int* __restrict__ src, const int* __restrict__ dst,
                  int* __restrict__ rowptr, int* __restrict__ col, int E, int N,
                  int GEMM_BLKS, int SCAT_BLKS) {
    __shared__ __attribute__((aligned(16))) unsigned short Ab[128 * 64];
    __shared__ __attribute__((aligned(16))) unsigned short Bb[128 * 64];
    const int bid = blockIdx.x;
    if (bid < GEMM_BLKS) {
        gemm_core<128, 128, 64, 64, 8>(Ab, Bb, A, Bt, Cc, a_src, a_dst, als, ald,
                                       M, 256, K, bid & 1, bid >> 1);
        return;
    }
    const int sb = bid - GEMM_BLKS;
    const int bin = sb / SCAT_BLKS;
    const int i = (sb - bin * SCAT_BLKS) * 256 + threadIdx.x;
    const int lo = (int)((long long)N * bin / 2);
    const int hi = (int)((long long)N * (bin + 1) / 2);
    int s, d;
    if (i < E) { d = dst[i]; s = src[i]; }
    else if (i < E + N) { d = i - E; s = d; }
    else return;
    if (d < lo || d >= hi) return;
    int pos = atomicAdd(&rowptr[d], 1);
    col[pos] = s;
}

// ---------------- standalone GEMM (+al) for layers 1, 2 ----------------

template <int BM, int BN, int WM, int WN, int H>
__global__ __launch_bounds__(256)
void gemm_bf16_al(const unsigned short* __restrict__ A, const unsigned short* __restrict__ Bt,
                  unsigned short* __restrict__ Cc,
                  const float* __restrict__ a_src, const float* __restrict__ a_dst,
                  float* __restrict__ als, float* __restrict__ ald,
                  int M, int Nn, int K) {
    __shared__ __attribute__((aligned(16))) unsigned short Ab[BM * 64];
    __shared__ __attribute__((aligned(16))) unsigned short Bb[BN * 64];
    gemm_core<BM, BN, WM, WN, H>(Ab, Bb, A, Bt, Cc, a_src, a_dst, als, ald,
                                 M, Nn, K, blockIdx.x, blockIdx.y);
}

// ---------------- H=8 aggregate: wave-per-node, fused edge weights ----------------

__global__ __launch_bounds__(256)
void gat_agg_w8(const unsigned short* __restrict__ hfeat,
                const float* __restrict__ als, const float* __restrict__ ald,
                const int* __restrict__ rowptr,           // shifted: rowptr[n] = END
                const int* __restrict__ col,
                const float* __restrict__ bias,
                unsigned short* __restrict__ outH,
                int N) {
    constexpr int CAP = 128;
    const int wid = threadIdx.x >> 6;
    const int lane = threadIdx.x & 63;
    const int n = blockIdx.x * 4 + wid;
    __shared__ float se_all[4][CAP * 8];
    __shared__ int scol_all[4][CAP];
    if (n >= N) return;
    float* se = se_all[wid];
    int* scol = scol_all[wid];

    const int r0 = (n == 0) ? 0 : rowptr[n - 1];
    const int deg = rowptr[n] - r0;
    const int dcap = min(deg, CAP);

    // stage col -> LDS (coalesced; same wave reads below, no barrier needed)
    for (int j = lane; j < dcap; j += 64) scol[j] = col[r0 + j];

    // ---- pass A: fused weights; slot = lane>>3 (edge), h = lane&7 (head) ----
    const int slot = lane >> 3, h = lane & 7;
    const float aldh = ald[(size_t)n * 8 + h];
    float psum = 0.f;
    for (int j = 0; j < deg; j += 8) {
        int e = j + slot;
        if (e < deg) {
            int s = (e < dcap) ? scol[e] : col[r0 + e];
            float ev = als[(size_t)s * 8 + h] + aldh;
            ev = LRELU(ev);
            float w = __expf(ev);
            psum += w;
            if (e < CAP) se[e * 8 + h] = w;
        }
    }
#pragma unroll
    for (int m = 8; m < 64; m <<= 1) psum += __shfl_xor(psum, m);
    const int q = lane >> 3;                 // this lane's head in pass B
    const float sinv = 1.0f / __shfl(psum, q);
    const float aldq = ald[(size_t)n * 8 + q];

    // ---- pass B: 4-deep gather ----
    const int cb = lane * 4;
    float a0 = 0.f, a1 = 0.f, a2 = 0.f, a3 = 0.f;
    int j = 0;
    for (; j + 3 < dcap; j += 4) {
        int s0 = __builtin_amdgcn_readfirstlane(scol[j]);
        int s1 = __builtin_amdgcn_readfirstlane(scol[j + 1]);
        int s2 = __builtin_amdgcn_readfirstlane(scol[j + 2]);
        int s3 = __builtin_amdgcn_readfirstlane(scol[j + 3]);
        ushort4v v0 = *(const ushort4v*)(hfeat + (size_t)s0 * 256 + cb);
        ushort4v v1 = *(const ushort4v*)(hfeat + (size_t)s1 * 256 + cb);
        ushort4v v2 = *(const ushort4v*)(hfeat + (size_t)s2 * 256 + cb);
        ushort4v v3 = *(const ushort4v*)(hfeat + (size_t)s3 * 256 + cb);
        float w0 = se[j * 8 + q];
        float w1 = se[j * 8 + 8 + q];
        float w2 = se[j * 8 + 16 + q];
        float w3 = se[j * 8 + 24 + q];
        a0 += bf2f(v0[0]) * w0; a1 += bf2f(v0[1]) * w0; a2 += bf2f(v0[2]) * w0; a3 += bf2f(v0[3]) * w0;
        a0 += bf2f(v1[0]) * w1; a1 += bf2f(v1[1]) * w1; a2 += bf2f(v1[2]) * w1; a3 += bf2f(v1[3]) * w1;
        a0 += bf2f(v2[0]) * w2; a1 += bf2f(v2[1]) * w2; a2 += bf2f(v2[2]) * w2; a3 += bf2f(v2[3]) * w2;
        a0 += bf2f(v3[0]) * w3; a1 += bf2f(v3[1]) * w3; a2 += bf2f(v3[2]) * w3; a3 += bf2f(v3[3]) * w3;
    }
    for (; j < dcap; j++) {
        int s0 = __builtin_amdgcn_readfirstlane(scol[j]);
        ushort4v v0 = *(const ushort4v*)(hfeat + (size_t)s0 * 256 + cb);
        float w0 = se[j * 8 + q];
        a0 += bf2f(v0[0]) * w0; a1 += bf2f(v0[1]) * w0; a2 += bf2f(v0[2]) * w0; a3 += bf2f(v0[3]) * w0;
    }
    for (; j < deg; j++) {                   // deg > CAP fallback (essentially never)
        int s0 = col[r0 + j];
        float ev = als[(size_t)s0 * 8 + q] + aldq;
        ev = LRELU(ev);
        float w0 = __expf(ev);
        ushort4v v0 = *(const ushort4v*)(hfeat + (size_t)s0 * 256 + cb);
        a0 += bf2f(v0[0]) * w0; a1 += bf2f(v0[1]) * w0; a2 += bf2f(v0[2]) * w0; a3 += bf2f(v0[3]) * w0;
    }

    // ---- epilogue: normalize + bias + relu + bf16 store ----
    float4 b4 = *(const float4*)&bias[cb];
    float o0 = fmaxf(a0 * sinv + b4.x, 0.f);
    float o1 = fmaxf(a1 * sinv + b4.y, 0.f);
    float o2 = fmaxf(a2 * sinv + b4.z, 0.f);
    float o3 = fmaxf(a3 * sinv + b4.w, 0.f);
    const size_t ob = (size_t)n * 256 + cb;
    *(ushort4v*)&outH[ob] = (ushort4v){f2bf(o0), f2bf(o1), f2bf(o2), f2bf(o3)};
}

// ---------------- H=1 aggregate + fused graph-pool (atomics) ----------------

__global__ __launch_bounds__(256)
void gat_agg_h1p(const unsigned short* __restrict__ hfeat,
                 const float* __restrict__ als, const float* __restrict__ ald,
                 const int* __restrict__ rowptr, const int* __restrict__ col,
                 const float* __restrict__ bias, const int* __restrict__ batch,
                 float* __restrict__ sums, int N) {
    constexpr int CAP = 256;
    const int wid = threadIdx.x >> 6;
    const int lane = threadIdx.x & 63;
    const int n = blockIdx.x * 4 + wid;
    __shared__ float sw_all[4][CAP];
    __shared__ int scol_all[4][CAP];
    if (n >= N) return;
    float* sw = sw_all[wid];
    int* scol = scol_all[wid];

    const int r0 = (n == 0) ? 0 : rowptr[n - 1];
    const int deg = rowptr[n] - r0;
    const int dcap = min(deg, CAP);
    const float aldn = ald[n];

    float lsum = 0.f;
    for (int idx = lane; idx < deg; idx += 64) {
        int s = col[r0 + idx];
        float ev = als[s] + aldn;
        ev = LRELU(ev);
        float w = __expf(ev);
        if (idx < CAP) { sw[idx] = w; scol[idx] = s; }
        lsum += w;
    }
#pragma unroll
    for (int m = 1; m < 64; m <<= 1) lsum += __shfl_xor(lsum, m);
    const float sinv = 1.0f / lsum;

    const int slot = lane >> 3, ch = lane & 7;
    float a0 = 0.f, a1 = 0.f, a2 = 0.f, a3 = 0.f;
    for (int j = 0; j < dcap; j += 8) {
        int e = j + slot;
        int ec = min(e, dcap - 1);
        int s = scol[ec];
        float w = (e < dcap) ? sw[ec] : 0.f;
        ushort4v v = *(const ushort4v*)(hfeat + (size_t)s * 32 + ch * 4);
        a0 += bf2f(v[0]) * w; a1 += bf2f(v[1]) * w;
        a2 += bf2f(v[2]) * w; a3 += bf2f(v[3]) * w;
    }
    for (int j = CAP; j < deg; j += 8) {     // deg > CAP fallback
        int e = j + slot;
        int ec = min(e, deg - 1);
        int s = col[r0 + ec];
        float w = 0.f;
        if (e < deg) {
            float ev = als[s] + aldn;
            ev = LRELU(ev);
            w = __expf(ev);
        }
        ushort4v v = *(const ushort4v*)(hfeat + (size_t)s * 32 + ch * 4);
        a0 += bf2f(v[0]) * w; a1 += bf2f(v[1]) * w;
        a2 += bf2f(v[2]) * w; a3 += bf2f(v[3]) * w;
    }
#pragma unroll
    for (int m = 8; m < 64; m <<= 1) {
        a0 += __shfl_xor(a0, m);
        a1 += __shfl_xor(a1, m);
        a2 += __shfl_xor(a2, m);
        a3 += __shfl_xor(a3, m);
    }
    if (slot == 0) {
        float4 b4 = *(const float4*)&bias[ch * 4];
        int g = batch[n];
        float* sp = &sums[(size_t)g * 32 + ch * 4];
        atomicAdd(&sp[0], a0 * sinv + b4.x);
        atomicAdd(&sp[1], a1 * sinv + b4.y);
        atomicAdd(&sp[2], a2 * sinv + b4.z);
        atomicAdd(&sp[3], a3 * sinv + b4.w);
    }
}

// ---------------- head: mean + linear ----------------

__global__ __launch_bounds__(64)
void head_kernel(const float* __restrict__ sums, const int* __restrict__ gstart,
                 const float* __restrict__ lin_w, const float* __restrict__ lin_b,
                 float* __restrict__ out) {
    const int g = blockIdx.x;
    const int tid = threadIdx.x;
    __shared__ float pm[32];
    if (tid < 32) {
        float cn = fmaxf((float)(gstart[g + 1] - gstart[g]), 1.f);
        pm[tid] = sums[(size_t)g * 32 + tid] / cn;
    }
    __syncthreads();
    float a = lin_b[tid];
#pragma unroll 8
    for (int cc = 0; cc < 32; cc++) a += pm[cc] * lin_w[cc * 64 + tid];
    out[(size_t)g * 64 + tid] = a;
}

// ---------------- launch ----------------

extern "C" void kernel_launch(void* const* d_in, const int* in_sizes, int n_in,
                              void* d_out, int out_size, void* d_ws, size_t ws_size,
                              hipStream_t stream) {
    const float* x     = (const float*)d_in[0];
    const int*   ei    = (const int*)d_in[1];
    const int*   batch = (const int*)d_in[2];
    const float* W0    = (const float*)d_in[3];
    const float* a_s0  = (const float*)d_in[4];
    const float* a_d0  = (const float*)d_in[5];
    const float* b0    = (const float*)d_in[6];
    const float* W1    = (const float*)d_in[7];
    const float* a_s1  = (const float*)d_in[8];
    const float* a_d1  = (const float*)d_in[9];
    const float* b1    = (const float*)d_in[10];
    const float* W2    = (const float*)d_in[11];
    const float* a_s2  = (const float*)d_in[12];
    const float* a_d2  = (const float*)d_in[13];
    const float* b2    = (const float*)d_in[14];
    const float* lin_w = (const float*)d_in[15];
    const float* lin_b = (const float*)d_in[16];

    const int N = in_sizes[0] / 128;   // 50000
    const int E = in_sizes[1] / 2;     // 1600000
    const int G = 256;
    const int Etot = E + N;
    const int* src = ei;
    const int* dst = ei + E;

    char* w = (char*)d_ws;
    size_t off = 0;
    auto alloc = [&](size_t bytes) -> void* {
        void* p = (void*)(w + off);
        off += (bytes + 255) & ~(size_t)255;
        return p;
    };
    // zero-region (one memset): deg, done, sums
    size_t zoff0 = off;
    int* deg    = (int*)alloc((size_t)N * 4);
    int* done   = (int*)alloc(4);
    float* sums = (float*)alloc((size_t)G * 32 * 4);
    size_t zbytes = off - zoff0;
    int* rowptr = (int*)alloc((size_t)(N + 1) * 4);
    int* colA   = (int*)alloc((size_t)Etot * 4);
    int* gstart = (int*)alloc((size_t)(G + 1) * 4);
    float* als  = (float*)alloc((size_t)N * 8 * 4);
    float* ald  = (float*)alloc((size_t)N * 8 * 4);
    unsigned short* hb  = (unsigned short*)alloc((size_t)N * 256 * 2);   // GEMM output
    unsigned short* g0  = (unsigned short*)alloc((size_t)N * 256 * 2);   // agg output
    unsigned short* w0t = (unsigned short*)alloc((size_t)256 * 128 * 2); // W0^T bf16
    unsigned short* w1t = (unsigned short*)alloc((size_t)256 * 256 * 2);
    unsigned short* w2t = (unsigned short*)alloc((size_t)32 * 256 * 2);
    unsigned short* xb = g0;                        // x bf16, aliased (dead before agg0 writes g0)

    hipMemsetAsync((void*)(w + zoff0), 0, zbytes, stream);

    // deg ∥ prep, + in-kernel scan/gstart (last deg block)
    {
        const int DEG_BLKS = (Etot + 255) / 256;
        long long prep_elems = (long long)N * 128 + 256 * 128 + 256 * 256 + 32 * 256;
        const int PREP_BLKS = (int)((prep_elems + 255) / 256);
        deg_prep_scan<<<DEG_BLKS + PREP_BLKS, 256, 0, stream>>>(
            dst, deg, E, N, x, W0, W1, W2, xb, w0t, w1t, w2t,
            DEG_BLKS, done, rowptr, batch, gstart, G);
    }

    const int MB = (N + 127) / 128;

    // gemm0(+al) ∥ 2-bin scatter (independent; agg0 needs both)
    {
        const int GEMM_BLKS = 2 * MB;
        const int SCAT_BLKS = (Etot + 255) / 256;
        mega0_kernel<<<GEMM_BLKS + 2 * SCAT_BLKS, 256, 0, stream>>>(
            xb, w0t, hb, a_s0, a_d0, als, ald, N, 128,
            src, dst, rowptr, colA, E, N, GEMM_BLKS, SCAT_BLKS);
    }
    gat_agg_w8<<<(N + 3) / 4, 256, 0, stream>>>(hb, als, ald, rowptr, colA, b0, g0, N);

    // layer 1: K=256
    gemm_bf16_al<128, 128, 64, 64, 8><<<dim3(2, MB), 256, 0, stream>>>(
        g0, w1t, hb, a_s1, a_d1, als, ald, N, 256, 256);
    gat_agg_w8<<<(N + 3) / 4, 256, 0, stream>>>(hb, als, ald, rowptr, colA, b1, g0, N);

    // layer 2: heads=1, C=32, K=256; pool fused into agg via atomics
    gemm_bf16_al<128, 32, 32, 32, 1><<<dim3(1, MB), 256, 0, stream>>>(
        g0, w2t, hb, a_s2, a_d2, als, ald, N, 32, 256);
    gat_agg_h1p<<<(N + 3) / 4, 256, 0, stream>>>(hb, als, ald, rowptr, colA, b2, batch, sums, N);

    // head: mean + linear
    head_kernel<<<G, 64, 0, stream>>>(sums, gstart, lin_w, lin_b, (float*)d_out);
}

// Round 15
// 653.339 us; speedup vs baseline: 1.4992x; 1.4992x over previous
//
#include <hip/hip_runtime.h>
#include <hip/hip_bf16.h>

// ---------------------------------------------------------------------------
// GAT (3 layers) + global mean pool + linear head.
// R15: revert R14's last-block-ticket scan (6450 device fences = 500 µs —
// measured); keep 2-bin scatter + atomic pool fusion. Structure: R13 build
// chain + R14's good deltas. agg8 at its ~3.8 TB/s random-gather floor.
// ---------------------------------------------------------------------------

#define LRELU(x) ((x) >= 0.f ? (x) : 0.2f * (x))

typedef unsigned short ushort8 __attribute__((ext_vector_type(8)));
typedef unsigned short ushort4v __attribute__((ext_vector_type(4)));
typedef __attribute__((ext_vector_type(8))) short bf16x8;
typedef __attribute__((ext_vector_type(4))) float f32x4;

__device__ __forceinline__ float bf2f(unsigned short u) {
    return __uint_as_float(((unsigned)u) << 16);
}
__device__ __forceinline__ unsigned short f2bf(float f) {
    __hip_bfloat16 b = __float2bfloat16(f);
    return *reinterpret_cast<unsigned short*>(&b);
}
__device__ __forceinline__ void gl_lds16(const unsigned short* g, unsigned short* l) {
    __builtin_amdgcn_global_load_lds((const __attribute__((address_space(1))) void*)g,
                                     (__attribute__((address_space(3))) void*)l, 16, 0, 0);
}

// ---------------- GEMM core ----------------
// C[M,Nn](bf16) = A[M,K](bf16) @ B[K,Nn], B transposed [Nn][K] bf16.
// Epilogue fuses attention logits (als/ald) via 16-lane shfl reduce.
// D layout: row = (lane>>4)*4 + reg, col = lane&15 (m89-verified, R5+ passed).

template <int BM, int BN, int WM, int WN, int H>
__device__ __forceinline__
void gemm_core(unsigned short* __restrict__ Ab, unsigned short* __restrict__ Bb,
               const unsigned short* __restrict__ A, const unsigned short* __restrict__ Bt,
               unsigned short* __restrict__ Cc,
               const float* __restrict__ a_src, const float* __restrict__ a_dst,
               float* __restrict__ als, float* __restrict__ ald,
               int M, int Nn, int K, int bxi, int byi) {
    constexpr int BK = 64;
    constexpr int MT = WM / 16, NT = WN / 16;
    constexpr int NWX = BN / WN;
    constexpr int NHL = WN / 32;
    const int tid = threadIdx.x;
    const int lane = tid & 63;
    const int wave = tid >> 6;
    const int wx = wave % NWX, wy = wave / NWX;
    const int by = byi * BM;
    const int bx = bxi * BN;
    const int r16 = lane & 15, kg = lane >> 4;
    const int srow = lane >> 3, sslot = lane & 7;

    f32x4 acc[MT][NT];
#pragma unroll
    for (int i = 0; i < MT; i++)
#pragma unroll
        for (int j = 0; j < NT; j++) acc[i][j] = (f32x4){0.f, 0.f, 0.f, 0.f};

    for (int k0 = 0; k0 < K; k0 += BK) {
        for (int t = wave; t < BM / 8; t += 4) {
            int gm = by + t * 8 + srow;
            if (gm >= M) gm = M - 1;              // clamp: garbage lands in unstored rows
            gl_lds16(A + (size_t)gm * K + k0 + sslot * 8, Ab + (t * 8) * BK);
        }
        for (int t = wave; t < BN / 8; t += 4) {
            int gn = bx + t * 8 + srow;
            gl_lds16(Bt + (size_t)gn * K + k0 + sslot * 8, Bb + (t * 8) * BK);
        }
        __syncthreads();
#pragma unroll
        for (int ks = 0; ks < 2; ks++) {
            bf16x8 bh[NT];
#pragma unroll
            for (int j = 0; j < NT; j++)
                bh[j] = *(const bf16x8*)(Bb + (wx * WN + j * 16 + r16) * BK + ks * 32 + kg * 8);
#pragma unroll
            for (int i = 0; i < MT; i++) {
                bf16x8 ah = *(const bf16x8*)(Ab + (wy * WM + i * 16 + r16) * BK + ks * 32 + kg * 8);
#pragma unroll
                for (int j = 0; j < NT; j++)
                    acc[i][j] = __builtin_amdgcn_mfma_f32_16x16x32_bf16(ah, bh[j], acc[i][j], 0, 0, 0);
            }
        }
        __syncthreads();
    }

    const int c0 = bx + wx * WN;
#pragma unroll
    for (int i = 0; i < MT; i++) {
#pragma unroll
        for (int r = 0; r < 4; r++) {
            int gm = by + wy * WM + i * 16 + kg * 4 + r;
            bool ok = gm < M;
            float sa[NHL] = {};
            float sd[NHL] = {};
#pragma unroll
            for (int j = 0; j < NT; j++) {
                int gn = c0 + j * 16 + r16;
                float v = acc[i][j][r];
                if (ok) Cc[(size_t)gm * Nn + gn] = f2bf(v);
                sa[j >> 1] += v * a_src[gn];
                sd[j >> 1] += v * a_dst[gn];
            }
#pragma unroll
            for (int m = 1; m < 16; m <<= 1) {
#pragma unroll
                for (int t = 0; t < NHL; t++) {
                    sa[t] += __shfl_xor(sa[t], m);
                    sd[t] += __shfl_xor(sd[t], m);
                }
            }
            if (ok && r16 == 0) {
#pragma unroll
                for (int t = 0; t < NHL; t++) {
                    int hh = (c0 >> 5) + t;
                    als[(size_t)gm * H + hh] = sa[t];
                    ald[(size_t)gm * H + hh] = sd[t];
                }
            }
        }
    }
}

// ---------------- deg ∥ prep (block-range fused, no fences) ----------------

__global__ __launch_bounds__(256)
void deg_prep_kernel(const int* __restrict__ dst, int* __restrict__ deg, int E, int N,
                     const float* __restrict__ x, const float* __restrict__ W0,
                     const float* __restrict__ W1, const float* __restrict__ W2,
                     unsigned short* __restrict__ xb, unsigned short* __restrict__ w0t,
                     unsigned short* __restrict__ w1t, unsigned short* __restrict__ w2t,
                     int DEG_BLKS) {
    if ((int)blockIdx.x < DEG_BLKS) {
        int i = blockIdx.x * 256 + threadIdx.x;
        if (i < E) atomicAdd(&deg[dst[i]], 1);
        else if (i < E + N) atomicAdd(&deg[i - E], 1);   // self loop
        return;
    }
    int i = (blockIdx.x - DEG_BLKS) * 256 + threadIdx.x;
    int nx = N * 128;
    if (i < nx) { xb[i] = f2bf(x[i]); return; }
    i -= nx;
    if (i < 256 * 128) {                          // W0 [128][256] -> w0t [256][128]
        int n = i / 128, k = i - n * 128;
        w0t[i] = f2bf(W0[(size_t)k * 256 + n]);
        return;
    }
    i -= 256 * 128;
    if (i < 256 * 256) {                          // W1 [256][256] -> w1t [256][256]
        int n = i / 256, k = i - n * 256;
        w1t[i] = f2bf(W1[(size_t)k * 256 + n]);
        return;
    }
    i -= 256 * 256;
    if (i < 32 * 256) {                           // W2 [256][32] -> w2t [32][256]
        int n = i / 256, k = i - n * 256;
        w2t[i] = f2bf(W2[(size_t)k * 32 + n]);
    }
}

// ---------------- scan + gstart (fused, single block) ----------------

__global__ void scan_kernel(const int* __restrict__ deg, int* __restrict__ rowptr, int n,
                            const int* __restrict__ batch, int* __restrict__ gstart,
                            int N, int G) {
    const int tid = threadIdx.x;
    if (tid <= G) {
        int lo = 0, hi = N;
        while (lo < hi) { int mid = (lo + hi) >> 1; if (batch[mid] < tid) lo = mid + 1; else hi = mid; }
        gstart[tid] = lo;
    }
    __shared__ int partial[1024];
    const int chunk = (n + 1023) / 1024;
    const int start = min(tid * chunk, n);
    const int end = min(start + chunk, n);
    int s = 0;
    for (int i = start; i < end; i++) s += deg[i];
    partial[tid] = s;
    __syncthreads();
    for (int o = 1; o < 1024; o <<= 1) {
        int v = (tid >= o) ? partial[tid - o] : 0;
        __syncthreads();
        partial[tid] += v;
        __syncthreads();
    }
    int run = (tid == 0) ? 0 : partial[tid - 1];
    for (int i = start; i < end; i++) { rowptr[i] = run; run += deg[i]; }
    if (tid == 0) rowptr[n] = partial[1023];
}

// ---------------- mega0: gemm0(+al) ∥ 2-bin scatter ----------------
// Bins write disjoint dst ranges -> order-independent. After both bins:
// rowptr[n] = END of segment n (shifted convention).

__global__ __launch_bounds__(256)
void mega0_kernel(const unsigned short* __restrict__ A, const unsigned short* __restrict__ Bt,
                  unsigned short* __restrict__ Cc,
                  const float* __restrict__ a_src, const float* __restrict__ a_dst,
                  float* __restrict__ als, float* __restrict__ ald, int M, int K,
                  const int* __restrict__ src, const int* __restrict__ dst,
                  int* __restrict__ rowptr, int* __restrict__ col, int E, int N,
                  int GEMM_BLKS, int SCAT_BLKS) {
    __shared__ __attribute__((aligned(16))) unsigned short Ab[128 * 64];
    __shared__ __attribute__((aligned(16))) unsigned short Bb[128 * 64];
    const int bid = blockIdx.x;
    if (bid < GEMM_BLKS) {
        gemm_core<128, 128, 64, 64, 8>(Ab, Bb, A, Bt, Cc, a_src, a_dst, als, ald,
                                       M, 256, K, bid & 1, bid >> 1);
        return;
    }
    const int sb = bid - GEMM_BLKS;
    const int bin = sb / SCAT_BLKS;
    const int i = (sb - bin * SCAT_BLKS) * 256 + threadIdx.x;
    const int lo = (int)((long long)N * bin / 2);
    const int hi = (int)((long long)N * (bin + 1) / 2);
    int s, d;
    if (i < E) { d = dst[i]; s = src[i]; }
    else if (i < E + N) { d = i - E; s = d; }
    else return;
    if (d < lo || d >= hi) return;
    int pos = atomicAdd(&rowptr[d], 1);
    col[pos] = s;
}

// ---------------- standalone GEMM (+al) for layers 1, 2 ----------------

template <int BM, int BN, int WM, int WN, int H>
__global__ __launch_bounds__(256)
void gemm_bf16_al(const unsigned short* __restrict__ A, const unsigned short* __restrict__ Bt,
                  unsigned short* __restrict__ Cc,
                  const float* __restrict__ a_src, const float* __restrict__ a_dst,
                  float* __restrict__ als, float* __restrict__ ald,
                  int M, int Nn, int K) {
    __shared__ __attribute__((aligned(16))) unsigned short Ab[BM * 64];
    __shared__ __attribute__((aligned(16))) unsigned short Bb[BN * 64];
    gemm_core<BM, BN, WM, WN, H>(Ab, Bb, A, Bt, Cc, a_src, a_dst, als, ald,
                                 M, Nn, K, blockIdx.x, blockIdx.y);
}

// ---------------- H=8 aggregate: wave-per-node, fused edge weights ----------------

__global__ __launch_bounds__(256)
void gat_agg_w8(const unsigned short* __restrict__ hfeat,
                const float* __restrict__ als, const float* __restrict__ ald,
                const int* __restrict__ rowptr,           // shifted: rowptr[n] = END
                const int* __restrict__ col,
                const float* __restrict__ bias,
                unsigned short* __restrict__ outH,
                int N) {
    constexpr int CAP = 128;
    const int wid = threadIdx.x >> 6;
    const int lane = threadIdx.x & 63;
    const int n = blockIdx.x * 4 + wid;
    __shared__ float se_all[4][CAP * 8];
    __shared__ int scol_all[4][CAP];
    if (n >= N) return;
    float* se = se_all[wid];
    int* scol = scol_all[wid];

    const int r0 = (n == 0) ? 0 : rowptr[n - 1];
    const int deg = rowptr[n] - r0;
    const int dcap = min(deg, CAP);

    // stage col -> LDS (coalesced; same wave reads below, no barrier needed)
    for (int j = lane; j < dcap; j += 64) scol[j] = col[r0 + j];

    // ---- pass A: fused weights; slot = lane>>3 (edge), h = lane&7 (head) ----
    const int slot = lane >> 3, h = lane & 7;
    const float aldh = ald[(size_t)n * 8 + h];
    float psum = 0.f;
    for (int j = 0; j < deg; j += 8) {
        int e = j + slot;
        if (e < deg) {
            int s = (e < dcap) ? scol[e] : col[r0 + e];
            float ev = als[(size_t)s * 8 + h] + aldh;
            ev = LRELU(ev);
            float w = __expf(ev);
            psum += w;
            if (e < CAP) se[e * 8 + h] = w;
        }
    }
#pragma unroll
    for (int m = 8; m < 64; m <<= 1) psum += __shfl_xor(psum, m);
    const int q = lane >> 3;                 // this lane's head in pass B
    const float sinv = 1.0f / __shfl(psum, q);
    const float aldq = ald[(size_t)n * 8 + q];

    // ---- pass B: 4-deep gather ----
    const int cb = lane * 4;
    float a0 = 0.f, a1 = 0.f, a2 = 0.f, a3 = 0.f;
    int j = 0;
    for (; j + 3 < dcap; j += 4) {
        int s0 = __builtin_amdgcn_readfirstlane(scol[j]);
        int s1 = __builtin_amdgcn_readfirstlane(scol[j + 1]);
        int s2 = __builtin_amdgcn_readfirstlane(scol[j + 2]);
        int s3 = __builtin_amdgcn_readfirstlane(scol[j + 3]);
        ushort4v v0 = *(const ushort4v*)(hfeat + (size_t)s0 * 256 + cb);
        ushort4v v1 = *(const ushort4v*)(hfeat + (size_t)s1 * 256 + cb);
        ushort4v v2 = *(const ushort4v*)(hfeat + (size_t)s2 * 256 + cb);
        ushort4v v3 = *(const ushort4v*)(hfeat + (size_t)s3 * 256 + cb);
        float w0 = se[j * 8 + q];
        float w1 = se[j * 8 + 8 + q];
        float w2 = se[j * 8 + 16 + q];
        float w3 = se[j * 8 + 24 + q];
        a0 += bf2f(v0[0]) * w0; a1 += bf2f(v0[1]) * w0; a2 += bf2f(v0[2]) * w0; a3 += bf2f(v0[3]) * w0;
        a0 += bf2f(v1[0]) * w1; a1 += bf2f(v1[1]) * w1; a2 += bf2f(v1[2]) * w1; a3 += bf2f(v1[3]) * w1;
        a0 += bf2f(v2[0]) * w2; a1 += bf2f(v2[1]) * w2; a2 += bf2f(v2[2]) * w2; a3 += bf2f(v2[3]) * w2;
        a0 += bf2f(v3[0]) * w3; a1 += bf2f(v3[1]) * w3; a2 += bf2f(v3[2]) * w3; a3 += bf2f(v3[3]) * w3;
    }
    for (; j < dcap; j++) {
        int s0 = __builtin_amdgcn_readfirstlane(scol[j]);
        ushort4v v0 = *(const ushort4v*)(hfeat + (size_t)s0 * 256 + cb);
        float w0 = se[j * 8 + q];
        a0 += bf2f(v0[0]) * w0; a1 += bf2f(v0[1]) * w0; a2 += bf2f(v0[2]) * w0; a3 += bf2f(v0[3]) * w0;
    }
    for (; j < deg; j++) {                   // deg > CAP fallback (essentially never)
        int s0 = col[r0 + j];
        float ev = als[(size_t)s0 * 8 + q] + aldq;
        ev = LRELU(ev);
        float w0 = __expf(ev);
        ushort4v v0 = *(const ushort4v*)(hfeat + (size_t)s0 * 256 + cb);
        a0 += bf2f(v0[0]) * w0; a1 += bf2f(v0[1]) * w0; a2 += bf2f(v0[2]) * w0; a3 += bf2f(v0[3]) * w0;
    }

    // ---- epilogue: normalize + bias + relu + bf16 store ----
    float4 b4 = *(const float4*)&bias[cb];
    float o0 = fmaxf(a0 * sinv + b4.x, 0.f);
    float o1 = fmaxf(a1 * sinv + b4.y, 0.f);
    float o2 = fmaxf(a2 * sinv + b4.z, 0.f);
    float o3 = fmaxf(a3 * sinv + b4.w, 0.f);
    const size_t ob = (size_t)n * 256 + cb;
    *(ushort4v*)&outH[ob] = (ushort4v){f2bf(o0), f2bf(o1), f2bf(o2), f2bf(o3)};
}

// ---------------- H=1 aggregate + fused graph-pool (atomics) ----------------

__global__ __launch_bounds__(256)
void gat_agg_h1p(const unsigned short* __restrict__ hfeat,
                 const float* __restrict__ als, const float* __restrict__ ald,
                 const int* __restrict__ rowptr, const int* __restrict__ col,
                 const float* __restrict__ bias, const int* __restrict__ batch,
                 float* __restrict__ sums, int N) {
    constexpr int CAP = 256;
    const int wid = threadIdx.x >> 6;
    const int lane = threadIdx.x & 63;
    const int n = blockIdx.x * 4 + wid;
    __shared__ float sw_all[4][CAP];
    __shared__ int scol_all[4][CAP];
    if (n >= N) return;
    float* sw = sw_all[wid];
    int* scol = scol_all[wid];

    const int r0 = (n == 0) ? 0 : rowptr[n - 1];
    const int deg = rowptr[n] - r0;
    const int dcap = min(deg, CAP);
    const float aldn = ald[n];

    float lsum = 0.f;
    for (int idx = lane; idx < deg; idx += 64) {
        int s = col[r0 + idx];
        float ev = als[s] + aldn;
        ev = LRELU(ev);
        float w = __expf(ev);
        if (idx < CAP) { sw[idx] = w; scol[idx] = s; }
        lsum += w;
    }
#pragma unroll
    for (int m = 1; m < 64; m <<= 1) lsum += __shfl_xor(lsum, m);
    const float sinv = 1.0f / lsum;

    const int slot = lane >> 3, ch = lane & 7;
    float a0 = 0.f, a1 = 0.f, a2 = 0.f, a3 = 0.f;
    for (int j = 0; j < dcap; j += 8) {
        int e = j + slot;
        int ec = min(e, dcap - 1);
        int s = scol[ec];
        float w = (e < dcap) ? sw[ec] : 0.f;
        ushort4v v = *(const ushort4v*)(hfeat + (size_t)s * 32 + ch * 4);
        a0 += bf2f(v[0]) * w; a1 += bf2f(v[1]) * w;
        a2 += bf2f(v[2]) * w; a3 += bf2f(v[3]) * w;
    }
    for (int j = CAP; j < deg; j += 8) {     // deg > CAP fallback
        int e = j + slot;
        int ec = min(e, deg - 1);
        int s = col[r0 + ec];
        float w = 0.f;
        if (e < deg) {
            float ev = als[s] + aldn;
            ev = LRELU(ev);
            w = __expf(ev);
        }
        ushort4v v = *(const ushort4v*)(hfeat + (size_t)s * 32 + ch * 4);
        a0 += bf2f(v[0]) * w; a1 += bf2f(v[1]) * w;
        a2 += bf2f(v[2]) * w; a3 += bf2f(v[3]) * w;
    }
#pragma unroll
    for (int m = 8; m < 64; m <<= 1) {
        a0 += __shfl_xor(a0, m);
        a1 += __shfl_xor(a1, m);
        a2 += __shfl_xor(a2, m);
        a3 += __shfl_xor(a3, m);
    }
    if (slot == 0) {
        float4 b4 = *(const float4*)&bias[ch * 4];
        int g = batch[n];
        float* sp = &sums[(size_t)g * 32 + ch * 4];
        atomicAdd(&sp[0], a0 * sinv + b4.x);
        atomicAdd(&sp[1], a1 * sinv + b4.y);
        atomicAdd(&sp[2], a2 * sinv + b4.z);
        atomicAdd(&sp[3], a3 * sinv + b4.w);
    }
}

// ---------------- head: mean + linear ----------------

__global__ __launch_bounds__(64)
void head_kernel(const float* __restrict__ sums, const int* __restrict__ gstart,
                 const float* __restrict__ lin_w, const float* __restrict__ lin_b,
                 float* __restrict__ out) {
    const int g = blockIdx.x;
    const int tid = threadIdx.x;
    __shared__ float pm[32];
    if (tid < 32) {
        float cn = fmaxf((float)(gstart[g + 1] - gstart[g]), 1.f);
        pm[tid] = sums[(size_t)g * 32 + tid] / cn;
    }
    __syncthreads();
    float a = lin_b[tid];
#pragma unroll 8
    for (int cc = 0; cc < 32; cc++) a += pm[cc] * lin_w[cc * 64 + tid];
    out[(size_t)g * 64 + tid] = a;
}

// ---------------- launch ----------------

extern "C" void kernel_launch(void* const* d_in, const int* in_sizes, int n_in,
                              void* d_out, int out_size, void* d_ws, size_t ws_size,
                              hipStream_t stream) {
    const float* x     = (const float*)d_in[0];
    const int*   ei    = (const int*)d_in[1];
    const int*   batch = (const int*)d_in[2];
    const float* W0    = (const float*)d_in[3];
    const float* a_s0  = (const float*)d_in[4];
    const float* a_d0  = (const float*)d_in[5];
    const float* b0    = (const float*)d_in[6];
    const float* W1    = (const float*)d_in[7];
    const float* a_s1  = (const float*)d_in[8];
    const float* a_d1  = (const float*)d_in[9];
    const float* b1    = (const float*)d_in[10];
    const float* W2    = (const float*)d_in[11];
    const float* a_s2  = (const float*)d_in[12];
    const float* a_d2  = (const float*)d_in[13];
    const float* b2    = (const float*)d_in[14];
    const float* lin_w = (const float*)d_in[15];
    const float* lin_b = (const float*)d_in[16];

    const int N = in_sizes[0] / 128;   // 50000
    const int E = in_sizes[1] / 2;     // 1600000
    const int G = 256;
    const int Etot = E + N;
    const int* src = ei;
    const int* dst = ei + E;

    char* w = (char*)d_ws;
    size_t off = 0;
    auto alloc = [&](size_t bytes) -> void* {
        void* p = (void*)(w + off);
        off += (bytes + 255) & ~(size_t)255;
        return p;
    };
    // zero-region (one memset): deg, sums
    size_t zoff0 = off;
    int* deg    = (int*)alloc((size_t)N * 4);
    float* sums = (float*)alloc((size_t)G * 32 * 4);
    size_t zbytes = off - zoff0;
    int* rowptr = (int*)alloc((size_t)(N + 1) * 4);
    int* colA   = (int*)alloc((size_t)Etot * 4);
    int* gstart = (int*)alloc((size_t)(G + 1) * 4);
    float* als  = (float*)alloc((size_t)N * 8 * 4);
    float* ald  = (float*)alloc((size_t)N * 8 * 4);
    unsigned short* hb  = (unsigned short*)alloc((size_t)N * 256 * 2);   // GEMM output
    unsigned short* g0  = (unsigned short*)alloc((size_t)N * 256 * 2);   // agg output
    unsigned short* w0t = (unsigned short*)alloc((size_t)256 * 128 * 2); // W0^T bf16
    unsigned short* w1t = (unsigned short*)alloc((size_t)256 * 256 * 2);
    unsigned short* w2t = (unsigned short*)alloc((size_t)32 * 256 * 2);
    unsigned short* xb = g0;                        // x bf16, aliased (dead before agg0 writes g0)

    hipMemsetAsync((void*)(w + zoff0), 0, zbytes, stream);

    // deg ∥ prep (independent; block-range fused)
    {
        const int DEG_BLKS = (Etot + 255) / 256;
        long long prep_elems = (long long)N * 128 + 256 * 128 + 256 * 256 + 32 * 256;
        const int PREP_BLKS = (int)((prep_elems + 255) / 256);
        deg_prep_kernel<<<DEG_BLKS + PREP_BLKS, 256, 0, stream>>>(
            dst, deg, E, N, x, W0, W1, W2, xb, w0t, w1t, w2t, DEG_BLKS);
    }

    // scan + gstart
    scan_kernel<<<1, 1024, 0, stream>>>(deg, rowptr, N, batch, gstart, N, G);

    const int MB = (N + 127) / 128;

    // gemm0(+al) ∥ 2-bin scatter (independent; agg0 needs both)
    {
        const int GEMM_BLKS = 2 * MB;
        const int SCAT_BLKS = (Etot + 255) / 256;
        mega0_kernel<<<GEMM_BLKS + 2 * SCAT_BLKS, 256, 0, stream>>>(
            xb, w0t, hb, a_s0, a_d0, als, ald, N, 128,
            src, dst, rowptr, colA, E, N, GEMM_BLKS, SCAT_BLKS);
    }
    gat_agg_w8<<<(N + 3) / 4, 256, 0, stream>>>(hb, als, ald, rowptr, colA, b0, g0, N);

    // layer 1: K=256
    gemm_bf16_al<128, 128, 64, 64, 8><<<dim3(2, MB), 256, 0, stream>>>(
        g0, w1t, hb, a_s1, a_d1, als, ald, N, 256, 256);
    gat_agg_w8<<<(N + 3) / 4, 256, 0, stream>>>(hb, als, ald, rowptr, colA, b1, g0, N);

    // layer 2: heads=1, C=32, K=256; pool fused into agg via atomics
    gemm_bf16_al<128, 32, 32, 32, 1><<<dim3(1, MB), 256, 0, stream>>>(
        g0, w2t, hb, a_s2, a_d2, als, ald, N, 32, 256);
    gat_agg_h1p<<<(N + 3) / 4, 256, 0, stream>>>(hb, als, ald, rowptr, colA, b2, batch, sums, N);

    // head: mean + linear
    head_kernel<<<G, 64, 0, stream>>>(sums, gstart, lin_w, lin_b, (float*)d_out);
}

// Round 16
// 645.065 us; speedup vs baseline: 1.5185x; 1.0128x over previous
//
#include <hip/hip_runtime.h>
#include <hip/hip_bf16.h>

// ---------------------------------------------------------------------------
// GAT (3 layers) + global mean pool + linear head.
// R16: revert R15's 2-bin scatter to R13's measured-good 4-bin (2-bin window
// reintroduced write amplification: WRITE 136 MB, mega0 127 µs). Keep
// deg∥prep fusion, gemm0∥scatter mega-kernel, al-fused GEMMs, atomic pool
// fusion. agg8 at its ~3.8 TB/s random-gather floor (R7-R13 invariant).
// ---------------------------------------------------------------------------

#define LRELU(x) ((x) >= 0.f ? (x) : 0.2f * (x))

typedef unsigned short ushort8 __attribute__((ext_vector_type(8)));
typedef unsigned short ushort4v __attribute__((ext_vector_type(4)));
typedef __attribute__((ext_vector_type(8))) short bf16x8;
typedef __attribute__((ext_vector_type(4))) float f32x4;

__device__ __forceinline__ float bf2f(unsigned short u) {
    return __uint_as_float(((unsigned)u) << 16);
}
__device__ __forceinline__ unsigned short f2bf(float f) {
    __hip_bfloat16 b = __float2bfloat16(f);
    return *reinterpret_cast<unsigned short*>(&b);
}
__device__ __forceinline__ void gl_lds16(const unsigned short* g, unsigned short* l) {
    __builtin_amdgcn_global_load_lds((const __attribute__((address_space(1))) void*)g,
                                     (__attribute__((address_space(3))) void*)l, 16, 0, 0);
}

// ---------------- GEMM core ----------------
// C[M,Nn](bf16) = A[M,K](bf16) @ B[K,Nn], B transposed [Nn][K] bf16.
// Epilogue fuses attention logits (als/ald) via 16-lane shfl reduce.
// D layout: row = (lane>>4)*4 + reg, col = lane&15 (m89-verified, R5+ passed).

template <int BM, int BN, int WM, int WN, int H>
__device__ __forceinline__
void gemm_core(unsigned short* __restrict__ Ab, unsigned short* __restrict__ Bb,
               const unsigned short* __restrict__ A, const unsigned short* __restrict__ Bt,
               unsigned short* __restrict__ Cc,
               const float* __restrict__ a_src, const float* __restrict__ a_dst,
               float* __restrict__ als, float* __restrict__ ald,
               int M, int Nn, int K, int bxi, int byi) {
    constexpr int BK = 64;
    constexpr int MT = WM / 16, NT = WN / 16;
    constexpr int NWX = BN / WN;
    constexpr int NHL = WN / 32;
    const int tid = threadIdx.x;
    const int lane = tid & 63;
    const int wave = tid >> 6;
    const int wx = wave % NWX, wy = wave / NWX;
    const int by = byi * BM;
    const int bx = bxi * BN;
    const int r16 = lane & 15, kg = lane >> 4;
    const int srow = lane >> 3, sslot = lane & 7;

    f32x4 acc[MT][NT];
#pragma unroll
    for (int i = 0; i < MT; i++)
#pragma unroll
        for (int j = 0; j < NT; j++) acc[i][j] = (f32x4){0.f, 0.f, 0.f, 0.f};

    for (int k0 = 0; k0 < K; k0 += BK) {
        for (int t = wave; t < BM / 8; t += 4) {
            int gm = by + t * 8 + srow;
            if (gm >= M) gm = M - 1;              // clamp: garbage lands in unstored rows
            gl_lds16(A + (size_t)gm * K + k0 + sslot * 8, Ab + (t * 8) * BK);
        }
        for (int t = wave; t < BN / 8; t += 4) {
            int gn = bx + t * 8 + srow;
            gl_lds16(Bt + (size_t)gn * K + k0 + sslot * 8, Bb + (t * 8) * BK);
        }
        __syncthreads();
#pragma unroll
        for (int ks = 0; ks < 2; ks++) {
            bf16x8 bh[NT];
#pragma unroll
            for (int j = 0; j < NT; j++)
                bh[j] = *(const bf16x8*)(Bb + (wx * WN + j * 16 + r16) * BK + ks * 32 + kg * 8);
#pragma unroll
            for (int i = 0; i < MT; i++) {
                bf16x8 ah = *(const bf16x8*)(Ab + (wy * WM + i * 16 + r16) * BK + ks * 32 + kg * 8);
#pragma unroll
                for (int j = 0; j < NT; j++)
                    acc[i][j] = __builtin_amdgcn_mfma_f32_16x16x32_bf16(ah, bh[j], acc[i][j], 0, 0, 0);
            }
        }
        __syncthreads();
    }

    const int c0 = bx + wx * WN;
#pragma unroll
    for (int i = 0; i < MT; i++) {
#pragma unroll
        for (int r = 0; r < 4; r++) {
            int gm = by + wy * WM + i * 16 + kg * 4 + r;
            bool ok = gm < M;
            float sa[NHL] = {};
            float sd[NHL] = {};
#pragma unroll
            for (int j = 0; j < NT; j++) {
                int gn = c0 + j * 16 + r16;
                float v = acc[i][j][r];
                if (ok) Cc[(size_t)gm * Nn + gn] = f2bf(v);
                sa[j >> 1] += v * a_src[gn];
                sd[j >> 1] += v * a_dst[gn];
            }
#pragma unroll
            for (int m = 1; m < 16; m <<= 1) {
#pragma unroll
                for (int t = 0; t < NHL; t++) {
                    sa[t] += __shfl_xor(sa[t], m);
                    sd[t] += __shfl_xor(sd[t], m);
                }
            }
            if (ok && r16 == 0) {
#pragma unroll
                for (int t = 0; t < NHL; t++) {
                    int hh = (c0 >> 5) + t;
                    als[(size_t)gm * H + hh] = sa[t];
                    ald[(size_t)gm * H + hh] = sd[t];
                }
            }
        }
    }
}

// ---------------- deg ∥ prep (block-range fused, no fences) ----------------

__global__ __launch_bounds__(256)
void deg_prep_kernel(const int* __restrict__ dst, int* __restrict__ deg, int E, int N,
                     const float* __restrict__ x, const float* __restrict__ W0,
                     const float* __restrict__ W1, const float* __restrict__ W2,
                     unsigned short* __restrict__ xb, unsigned short* __restrict__ w0t,
                     unsigned short* __restrict__ w1t, unsigned short* __restrict__ w2t,
                     int DEG_BLKS) {
    if ((int)blockIdx.x < DEG_BLKS) {
        int i = blockIdx.x * 256 + threadIdx.x;
        if (i < E) atomicAdd(&deg[dst[i]], 1);
        else if (i < E + N) atomicAdd(&deg[i - E], 1);   // self loop
        return;
    }
    int i = (blockIdx.x - DEG_BLKS) * 256 + threadIdx.x;
    int nx = N * 128;
    if (i < nx) { xb[i] = f2bf(x[i]); return; }
    i -= nx;
    if (i < 256 * 128) {                          // W0 [128][256] -> w0t [256][128]
        int n = i / 128, k = i - n * 128;
        w0t[i] = f2bf(W0[(size_t)k * 256 + n]);
        return;
    }
    i -= 256 * 128;
    if (i < 256 * 256) {                          // W1 [256][256] -> w1t [256][256]
        int n = i / 256, k = i - n * 256;
        w1t[i] = f2bf(W1[(size_t)k * 256 + n]);
        return;
    }
    i -= 256 * 256;
    if (i < 32 * 256) {                           // W2 [256][32] -> w2t [32][256]
        int n = i / 256, k = i - n * 256;
        w2t[i] = f2bf(W2[(size_t)k * 32 + n]);
    }
}

// ---------------- scan + gstart (fused, single block) ----------------

__global__ void scan_kernel(const int* __restrict__ deg, int* __restrict__ rowptr, int n,
                            const int* __restrict__ batch, int* __restrict__ gstart,
                            int N, int G) {
    const int tid = threadIdx.x;
    if (tid <= G) {
        int lo = 0, hi = N;
        while (lo < hi) { int mid = (lo + hi) >> 1; if (batch[mid] < tid) lo = mid + 1; else hi = mid; }
        gstart[tid] = lo;
    }
    __shared__ int partial[1024];
    const int chunk = (n + 1023) / 1024;
    const int start = min(tid * chunk, n);
    const int end = min(start + chunk, n);
    int s = 0;
    for (int i = start; i < end; i++) s += deg[i];
    partial[tid] = s;
    __syncthreads();
    for (int o = 1; o < 1024; o <<= 1) {
        int v = (tid >= o) ? partial[tid - o] : 0;
        __syncthreads();
        partial[tid] += v;
        __syncthreads();
    }
    int run = (tid == 0) ? 0 : partial[tid - 1];
    for (int i = start; i < end; i++) { rowptr[i] = run; run += deg[i]; }
    if (tid == 0) rowptr[n] = partial[1023];
}

// ---------------- mega0: gemm0(+al) ∥ 4-bin scatter ----------------
// gemm blocks first (MFMA-bound); scatter bins follow in block-ID order
// (~sequential: blocks/bin >> resident blocks) -> R6 write locality (1.6 MB
// window/bin). Bins write disjoint dst ranges -> order-independent. After
// all bins: rowptr[n] = END of segment n (shifted convention).

__global__ __launch_bounds__(256)
void mega0_kernel(const unsigned short* __restrict__ A, const unsigned short* __restrict__ Bt,
                  unsigned short* __restrict__ Cc,
                  const float* __restrict__ a_src, const float* __restrict__ a_dst,
                  float* __restrict__ als, float* __restrict__ ald, int M, int K,
                  const int* __restrict__ src, const int* __restrict__ dst,
                  int* __restrict__ rowptr, int* __restrict__ col, int E, int N,
                  int GEMM_BLKS, int SCAT_BLKS) {
    __shared__ __attribute__((aligned(16))) unsigned short Ab[128 * 64];
    __shared__ __attribute__((aligned(16))) unsigned short Bb[128 * 64];
    const int bid = blockIdx.x;
    if (bid < GEMM_BLKS) {
        gemm_core<128, 128, 64, 64, 8>(Ab, Bb, A, Bt, Cc, a_src, a_dst, als, ald,
                                       M, 256, K, bid & 1, bid >> 1);
        return;
    }
    const int sb = bid - GEMM_BLKS;
    const int bin = sb / SCAT_BLKS;
    const int i = (sb - bin * SCAT_BLKS) * 256 + threadIdx.x;
    const int lo = (int)((long long)N * bin / 4);
    const int hi = (int)((long long)N * (bin + 1) / 4);
    int s, d;
    if (i < E) { d = dst[i]; s = src[i]; }
    else if (i < E + N) { d = i - E; s = d; }
    else return;
    if (d < lo || d >= hi) return;
    int pos = atomicAdd(&rowptr[d], 1);
    col[pos] = s;
}

// ---------------- standalone GEMM (+al) for layers 1, 2 ----------------

template <int BM, int BN, int WM, int WN, int H>
__global__ __launch_bounds__(256)
void gemm_bf16_al(const unsigned short* __restrict__ A, const unsigned short* __restrict__ Bt,
                  unsigned short* __restrict__ Cc,
                  const float* __restrict__ a_src, const float* __restrict__ a_dst,
                  float* __restrict__ als, float* __restrict__ ald,
                  int M, int Nn, int K) {
    __shared__ __attribute__((aligned(16))) unsigned short Ab[BM * 64];
    __shared__ __attribute__((aligned(16))) unsigned short Bb[BN * 64];
    gemm_core<BM, BN, WM, WN, H>(Ab, Bb, A, Bt, Cc, a_src, a_dst, als, ald,
                                 M, Nn, K, blockIdx.x, blockIdx.y);
}

// ---------------- H=8 aggregate: wave-per-node, fused edge weights ----------------

__global__ __launch_bounds__(256)
void gat_agg_w8(const unsigned short* __restrict__ hfeat,
                const float* __restrict__ als, const float* __restrict__ ald,
                const int* __restrict__ rowptr,           // shifted: rowptr[n] = END
                const int* __restrict__ col,
                const float* __restrict__ bias,
                unsigned short* __restrict__ outH,
                int N) {
    constexpr int CAP = 128;
    const int wid = threadIdx.x >> 6;
    const int lane = threadIdx.x & 63;
    const int n = blockIdx.x * 4 + wid;
    __shared__ float se_all[4][CAP * 8];
    __shared__ int scol_all[4][CAP];
    if (n >= N) return;
    float* se = se_all[wid];
    int* scol = scol_all[wid];

    const int r0 = (n == 0) ? 0 : rowptr[n - 1];
    const int deg = rowptr[n] - r0;
    const int dcap = min(deg, CAP);

    // stage col -> LDS (coalesced; same wave reads below, no barrier needed)
    for (int j = lane; j < dcap; j += 64) scol[j] = col[r0 + j];

    // ---- pass A: fused weights; slot = lane>>3 (edge), h = lane&7 (head) ----
    const int slot = lane >> 3, h = lane & 7;
    const float aldh = ald[(size_t)n * 8 + h];
    float psum = 0.f;
    for (int j = 0; j < deg; j += 8) {
        int e = j + slot;
        if (e < deg) {
            int s = (e < dcap) ? scol[e] : col[r0 + e];
            float ev = als[(size_t)s * 8 + h] + aldh;
            ev = LRELU(ev);
            float w = __expf(ev);
            psum += w;
            if (e < CAP) se[e * 8 + h] = w;
        }
    }
#pragma unroll
    for (int m = 8; m < 64; m <<= 1) psum += __shfl_xor(psum, m);
    const int q = lane >> 3;                 // this lane's head in pass B
    const float sinv = 1.0f / __shfl(psum, q);
    const float aldq = ald[(size_t)n * 8 + q];

    // ---- pass B: 4-deep gather ----
    const int cb = lane * 4;
    float a0 = 0.f, a1 = 0.f, a2 = 0.f, a3 = 0.f;
    int j = 0;
    for (; j + 3 < dcap; j += 4) {
        int s0 = __builtin_amdgcn_readfirstlane(scol[j]);
        int s1 = __builtin_amdgcn_readfirstlane(scol[j + 1]);
        int s2 = __builtin_amdgcn_readfirstlane(scol[j + 2]);
        int s3 = __builtin_amdgcn_readfirstlane(scol[j + 3]);
        ushort4v v0 = *(const ushort4v*)(hfeat + (size_t)s0 * 256 + cb);
        ushort4v v1 = *(const ushort4v*)(hfeat + (size_t)s1 * 256 + cb);
        ushort4v v2 = *(const ushort4v*)(hfeat + (size_t)s2 * 256 + cb);
        ushort4v v3 = *(const ushort4v*)(hfeat + (size_t)s3 * 256 + cb);
        float w0 = se[j * 8 + q];
        float w1 = se[j * 8 + 8 + q];
        float w2 = se[j * 8 + 16 + q];
        float w3 = se[j * 8 + 24 + q];
        a0 += bf2f(v0[0]) * w0; a1 += bf2f(v0[1]) * w0; a2 += bf2f(v0[2]) * w0; a3 += bf2f(v0[3]) * w0;
        a0 += bf2f(v1[0]) * w1; a1 += bf2f(v1[1]) * w1; a2 += bf2f(v1[2]) * w1; a3 += bf2f(v1[3]) * w1;
        a0 += bf2f(v2[0]) * w2; a1 += bf2f(v2[1]) * w2; a2 += bf2f(v2[2]) * w2; a3 += bf2f(v2[3]) * w2;
        a0 += bf2f(v3[0]) * w3; a1 += bf2f(v3[1]) * w3; a2 += bf2f(v3[2]) * w3; a3 += bf2f(v3[3]) * w3;
    }
    for (; j < dcap; j++) {
        int s0 = __builtin_amdgcn_readfirstlane(scol[j]);
        ushort4v v0 = *(const ushort4v*)(hfeat + (size_t)s0 * 256 + cb);
        float w0 = se[j * 8 + q];
        a0 += bf2f(v0[0]) * w0; a1 += bf2f(v0[1]) * w0; a2 += bf2f(v0[2]) * w0; a3 += bf2f(v0[3]) * w0;
    }
    for (; j < deg; j++) {                   // deg > CAP fallback (essentially never)
        int s0 = col[r0 + j];
        float ev = als[(size_t)s0 * 8 + q] + aldq;
        ev = LRELU(ev);
        float w0 = __expf(ev);
        ushort4v v0 = *(const ushort4v*)(hfeat + (size_t)s0 * 256 + cb);
        a0 += bf2f(v0[0]) * w0; a1 += bf2f(v0[1]) * w0; a2 += bf2f(v0[2]) * w0; a3 += bf2f(v0[3]) * w0;
    }

    // ---- epilogue: normalize + bias + relu + bf16 store ----
    float4 b4 = *(const float4*)&bias[cb];
    float o0 = fmaxf(a0 * sinv + b4.x, 0.f);
    float o1 = fmaxf(a1 * sinv + b4.y, 0.f);
    float o2 = fmaxf(a2 * sinv + b4.z, 0.f);
    float o3 = fmaxf(a3 * sinv + b4.w, 0.f);
    const size_t ob = (size_t)n * 256 + cb;
    *(ushort4v*)&outH[ob] = (ushort4v){f2bf(o0), f2bf(o1), f2bf(o2), f2bf(o3)};
}

// ---------------- H=1 aggregate + fused graph-pool (atomics) ----------------

__global__ __launch_bounds__(256)
void gat_agg_h1p(const unsigned short* __restrict__ hfeat,
                 const float* __restrict__ als, const float* __restrict__ ald,
                 const int* __restrict__ rowptr, const int* __restrict__ col,
                 const float* __restrict__ bias, const int* __restrict__ batch,
                 float* __restrict__ sums, int N) {
    constexpr int CAP = 256;
    const int wid = threadIdx.x >> 6;
    const int lane = threadIdx.x & 63;
    const int n = blockIdx.x * 4 + wid;
    __shared__ float sw_all[4][CAP];
    __shared__ int scol_all[4][CAP];
    if (n >= N) return;
    float* sw = sw_all[wid];
    int* scol = scol_all[wid];

    const int r0 = (n == 0) ? 0 : rowptr[n - 1];
    const int deg = rowptr[n] - r0;
    const int dcap = min(deg, CAP);
    const float aldn = ald[n];

    float lsum = 0.f;
    for (int idx = lane; idx < deg; idx += 64) {
        int s = col[r0 + idx];
        float ev = als[s] + aldn;
        ev = LRELU(ev);
        float w = __expf(ev);
        if (idx < CAP) { sw[idx] = w; scol[idx] = s; }
        lsum += w;
    }
#pragma unroll
    for (int m = 1; m < 64; m <<= 1) lsum += __shfl_xor(lsum, m);
    const float sinv = 1.0f / lsum;

    const int slot = lane >> 3, ch = lane & 7;
    float a0 = 0.f, a1 = 0.f, a2 = 0.f, a3 = 0.f;
    for (int j = 0; j < dcap; j += 8) {
        int e = j + slot;
        int ec = min(e, dcap - 1);
        int s = scol[ec];
        float w = (e < dcap) ? sw[ec] : 0.f;
        ushort4v v = *(const ushort4v*)(hfeat + (size_t)s * 32 + ch * 4);
        a0 += bf2f(v[0]) * w; a1 += bf2f(v[1]) * w;
        a2 += bf2f(v[2]) * w; a3 += bf2f(v[3]) * w;
    }
    for (int j = CAP; j < deg; j += 8) {     // deg > CAP fallback
        int e = j + slot;
        int ec = min(e, deg - 1);
        int s = col[r0 + ec];
        float w = 0.f;
        if (e < deg) {
            float ev = als[s] + aldn;
            ev = LRELU(ev);
            w = __expf(ev);
        }
        ushort4v v = *(const ushort4v*)(hfeat + (size_t)s * 32 + ch * 4);
        a0 += bf2f(v[0]) * w; a1 += bf2f(v[1]) * w;
        a2 += bf2f(v[2]) * w; a3 += bf2f(v[3]) * w;
    }
#pragma unroll
    for (int m = 8; m < 64; m <<= 1) {
        a0 += __shfl_xor(a0, m);
        a1 += __shfl_xor(a1, m);
        a2 += __shfl_xor(a2, m);
        a3 += __shfl_xor(a3, m);
    }
    if (slot == 0) {
        float4 b4 = *(const float4*)&bias[ch * 4];
        int g = batch[n];
        float* sp = &sums[(size_t)g * 32 + ch * 4];
        atomicAdd(&sp[0], a0 * sinv + b4.x);
        atomicAdd(&sp[1], a1 * sinv + b4.y);
        atomicAdd(&sp[2], a2 * sinv + b4.z);
        atomicAdd(&sp[3], a3 * sinv + b4.w);
    }
}

// ---------------- head: mean + linear ----------------

__global__ __launch_bounds__(64)
void head_kernel(const float* __restrict__ sums, const int* __restrict__ gstart,
                 const float* __restrict__ lin_w, const float* __restrict__ lin_b,
                 float* __restrict__ out) {
    const int g = blockIdx.x;
    const int tid = threadIdx.x;
    __shared__ float pm[32];
    if (tid < 32) {
        float cn = fmaxf((float)(gstart[g + 1] - gstart[g]), 1.f);
        pm[tid] = sums[(size_t)g * 32 + tid] / cn;
    }
    __syncthreads();
    float a = lin_b[tid];
#pragma unroll 8
    for (int cc = 0; cc < 32; cc++) a += pm[cc] * lin_w[cc * 64 + tid];
    out[(size_t)g * 64 + tid] = a;
}

// ---------------- launch ----------------

extern "C" void kernel_launch(void* const* d_in, const int* in_sizes, int n_in,
                              void* d_out, int out_size, void* d_ws, size_t ws_size,
                              hipStream_t stream) {
    const float* x     = (const float*)d_in[0];
    const int*   ei    = (const int*)d_in[1];
    const int*   batch = (const int*)d_in[2];
    const float* W0    = (const float*)d_in[3];
    const float* a_s0  = (const float*)d_in[4];
    const float* a_d0  = (const float*)d_in[5];
    const float* b0    = (const float*)d_in[6];
    const float* W1    = (const float*)d_in[7];
    const float* a_s1  = (const float*)d_in[8];
    const float* a_d1  = (const float*)d_in[9];
    const float* b1    = (const float*)d_in[10];
    const float* W2    = (const float*)d_in[11];
    const float* a_s2  = (const float*)d_in[12];
    const float* a_d2  = (const float*)d_in[13];
    const float* b2    = (const float*)d_in[14];
    const float* lin_w = (const float*)d_in[15];
    const float* lin_b = (const float*)d_in[16];

    const int N = in_sizes[0] / 128;   // 50000
    const int E = in_sizes[1] / 2;     // 1600000
    const int G = 256;
    const int Etot = E + N;
    const int* src = ei;
    const int* dst = ei + E;

    char* w = (char*)d_ws;
    size_t off = 0;
    auto alloc = [&](size_t bytes) -> void* {
        void* p = (void*)(w + off);
        off += (bytes + 255) & ~(size_t)255;
        return p;
    };
    // zero-region (one memset): deg, sums
    size_t zoff0 = off;
    int* deg    = (int*)alloc((size_t)N * 4);
    float* sums = (float*)alloc((size_t)G * 32 * 4);
    size_t zbytes = off - zoff0;
    int* rowptr = (int*)alloc((size_t)(N + 1) * 4);
    int* colA   = (int*)alloc((size_t)Etot * 4);
    int* gstart = (int*)alloc((size_t)(G + 1) * 4);
    float* als  = (float*)alloc((size_t)N * 8 * 4);
    float* ald  = (float*)alloc((size_t)N * 8 * 4);
    unsigned short* hb  = (unsigned short*)alloc((size_t)N * 256 * 2);   // GEMM output
    unsigned short* g0  = (unsigned short*)alloc((size_t)N * 256 * 2);   // agg output
    unsigned short* w0t = (unsigned short*)alloc((size_t)256 * 128 * 2); // W0^T bf16
    unsigned short* w1t = (unsigned short*)alloc((size_t)256 * 256 * 2);
    unsigned short* w2t = (unsigned short*)alloc((size_t)32 * 256 * 2);
    unsigned short* xb = g0;                        // x bf16, aliased (dead before agg0 writes g0)

    hipMemsetAsync((void*)(w + zoff0), 0, zbytes, stream);

    // deg ∥ prep (independent; block-range fused)
    {
        const int DEG_BLKS = (Etot + 255) / 256;
        long long prep_elems = (long long)N * 128 + 256 * 128 + 256 * 256 + 32 * 256;
        const int PREP_BLKS = (int)((prep_elems + 255) / 256);
        deg_prep_kernel<<<DEG_BLKS + PREP_BLKS, 256, 0, stream>>>(
            dst, deg, E, N, x, W0, W1, W2, xb, w0t, w1t, w2t, DEG_BLKS);
    }

    // scan + gstart
    scan_kernel<<<1, 1024, 0, stream>>>(deg, rowptr, N, batch, gstart, N, G);

    const int MB = (N + 127) / 128;

    // gemm0(+al) ∥ 4-bin scatter (independent; agg0 needs both)
    {
        const int GEMM_BLKS = 2 * MB;
        const int SCAT_BLKS = (Etot + 255) / 256;
        mega0_kernel<<<GEMM_BLKS + 4 * SCAT_BLKS, 256, 0, stream>>>(
            xb, w0t, hb, a_s0, a_d0, als, ald, N, 128,
            src, dst, rowptr, colA, E, N, GEMM_BLKS, SCAT_BLKS);
    }
    gat_agg_w8<<<(N + 3) / 4, 256, 0, stream>>>(hb, als, ald, rowptr, colA, b0, g0, N);

    // layer 1: K=256
    gemm_bf16_al<128, 128, 64, 64, 8><<<dim3(2, MB), 256, 0, stream>>>(
        g0, w1t, hb, a_s1, a_d1, als, ald, N, 256, 256);
    gat_agg_w8<<<(N + 3) / 4, 256, 0, stream>>>(hb, als, ald, rowptr, colA, b1, g0, N);

    // layer 2: heads=1, C=32, K=256; pool fused into agg via atomics
    gemm_bf16_al<128, 32, 32, 32, 1><<<dim3(1, MB), 256, 0, stream>>>(
        g0, w2t, hb, a_s2, a_d2, als, ald, N, 32, 256);
    gat_agg_h1p<<<(N + 3) / 4, 256, 0, stream>>>(hb, als, ald, rowptr, colA, b2, batch, sums, N);

    // head: mean + linear
    head_kernel<<<G, 64, 0, stream>>>(sums, gstart, lin_w, lin_b, (float*)d_out);
}

// Round 17
// 582.470 us; speedup vs baseline: 1.6817x; 1.1075x over previous
//
#include <hip/hip_runtime.h>
#include <hip/hip_bf16.h>

// ---------------------------------------------------------------------------
// GAT (3 layers) + global mean pool + linear head.
// R17: exact revert to R13 (measured best, 580 µs). Experiments ledger:
// ticket-scan ✗ (device fences, 500 µs), 2-bin scatter ✗ (write amp),
// atomic pool fusion ✗ (sorted batch -> per-line contention, +65 µs).
// Kept: deg∥prep fusion, mega0 = gemm0∥4-bin scatter, al-fused GEMMs,
// wave-per-node aggs. agg8 at its ~3.8 TB/s random-gather floor.
// ---------------------------------------------------------------------------

#define LRELU(x) ((x) >= 0.f ? (x) : 0.2f * (x))

typedef unsigned short ushort8 __attribute__((ext_vector_type(8)));
typedef unsigned short ushort4v __attribute__((ext_vector_type(4)));
typedef __attribute__((ext_vector_type(8))) short bf16x8;
typedef __attribute__((ext_vector_type(4))) float f32x4;

__device__ __forceinline__ float bf2f(unsigned short u) {
    return __uint_as_float(((unsigned)u) << 16);
}
__device__ __forceinline__ unsigned short f2bf(float f) {
    __hip_bfloat16 b = __float2bfloat16(f);
    return *reinterpret_cast<unsigned short*>(&b);
}
__device__ __forceinline__ void gl_lds16(const unsigned short* g, unsigned short* l) {
    __builtin_amdgcn_global_load_lds((const __attribute__((address_space(1))) void*)g,
                                     (__attribute__((address_space(3))) void*)l, 16, 0, 0);
}

// ---------------- GEMM core ----------------
// C[M,Nn](bf16) = A[M,K](bf16) @ B[K,Nn], B transposed [Nn][K] bf16.
// Epilogue fuses attention logits (als/ald) via 16-lane shfl reduce.
// D layout: row = (lane>>4)*4 + reg, col = lane&15 (m89-verified, R5+ passed).

template <int BM, int BN, int WM, int WN, int H>
__device__ __forceinline__
void gemm_core(unsigned short* __restrict__ Ab, unsigned short* __restrict__ Bb,
               const unsigned short* __restrict__ A, const unsigned short* __restrict__ Bt,
               unsigned short* __restrict__ Cc,
               const float* __restrict__ a_src, const float* __restrict__ a_dst,
               float* __restrict__ als, float* __restrict__ ald,
               int M, int Nn, int K, int bxi, int byi) {
    constexpr int BK = 64;
    constexpr int MT = WM / 16, NT = WN / 16;
    constexpr int NWX = BN / WN;
    constexpr int NHL = WN / 32;
    const int tid = threadIdx.x;
    const int lane = tid & 63;
    const int wave = tid >> 6;
    const int wx = wave % NWX, wy = wave / NWX;
    const int by = byi * BM;
    const int bx = bxi * BN;
    const int r16 = lane & 15, kg = lane >> 4;
    const int srow = lane >> 3, sslot = lane & 7;

    f32x4 acc[MT][NT];
#pragma unroll
    for (int i = 0; i < MT; i++)
#pragma unroll
        for (int j = 0; j < NT; j++) acc[i][j] = (f32x4){0.f, 0.f, 0.f, 0.f};

    for (int k0 = 0; k0 < K; k0 += BK) {
        for (int t = wave; t < BM / 8; t += 4) {
            int gm = by + t * 8 + srow;
            if (gm >= M) gm = M - 1;              // clamp: garbage lands in unstored rows
            gl_lds16(A + (size_t)gm * K + k0 + sslot * 8, Ab + (t * 8) * BK);
        }
        for (int t = wave; t < BN / 8; t += 4) {
            int gn = bx + t * 8 + srow;
            gl_lds16(Bt + (size_t)gn * K + k0 + sslot * 8, Bb + (t * 8) * BK);
        }
        __syncthreads();
#pragma unroll
        for (int ks = 0; ks < 2; ks++) {
            bf16x8 bh[NT];
#pragma unroll
            for (int j = 0; j < NT; j++)
                bh[j] = *(const bf16x8*)(Bb + (wx * WN + j * 16 + r16) * BK + ks * 32 + kg * 8);
#pragma unroll
            for (int i = 0; i < MT; i++) {
                bf16x8 ah = *(const bf16x8*)(Ab + (wy * WM + i * 16 + r16) * BK + ks * 32 + kg * 8);
#pragma unroll
                for (int j = 0; j < NT; j++)
                    acc[i][j] = __builtin_amdgcn_mfma_f32_16x16x32_bf16(ah, bh[j], acc[i][j], 0, 0, 0);
            }
        }
        __syncthreads();
    }

    const int c0 = bx + wx * WN;
#pragma unroll
    for (int i = 0; i < MT; i++) {
#pragma unroll
        for (int r = 0; r < 4; r++) {
            int gm = by + wy * WM + i * 16 + kg * 4 + r;
            bool ok = gm < M;
            float sa[NHL] = {};
            float sd[NHL] = {};
#pragma unroll
            for (int j = 0; j < NT; j++) {
                int gn = c0 + j * 16 + r16;
                float v = acc[i][j][r];
                if (ok) Cc[(size_t)gm * Nn + gn] = f2bf(v);
                sa[j >> 1] += v * a_src[gn];
                sd[j >> 1] += v * a_dst[gn];
            }
#pragma unroll
            for (int m = 1; m < 16; m <<= 1) {
#pragma unroll
                for (int t = 0; t < NHL; t++) {
                    sa[t] += __shfl_xor(sa[t], m);
                    sd[t] += __shfl_xor(sd[t], m);
                }
            }
            if (ok && r16 == 0) {
#pragma unroll
                for (int t = 0; t < NHL; t++) {
                    int hh = (c0 >> 5) + t;
                    als[(size_t)gm * H + hh] = sa[t];
                    ald[(size_t)gm * H + hh] = sd[t];
                }
            }
        }
    }
}

// ---------------- deg ∥ prep (block-range fused, no fences) ----------------

__global__ __launch_bounds__(256)
void deg_prep_kernel(const int* __restrict__ dst, int* __restrict__ deg, int E, int N,
                     const float* __restrict__ x, const float* __restrict__ W0,
                     const float* __restrict__ W1, const float* __restrict__ W2,
                     unsigned short* __restrict__ xb, unsigned short* __restrict__ w0t,
                     unsigned short* __restrict__ w1t, unsigned short* __restrict__ w2t,
                     int DEG_BLKS) {
    if ((int)blockIdx.x < DEG_BLKS) {
        int i = blockIdx.x * 256 + threadIdx.x;
        if (i < E) atomicAdd(&deg[dst[i]], 1);
        else if (i < E + N) atomicAdd(&deg[i - E], 1);   // self loop
        return;
    }
    int i = (blockIdx.x - DEG_BLKS) * 256 + threadIdx.x;
    int nx = N * 128;
    if (i < nx) { xb[i] = f2bf(x[i]); return; }
    i -= nx;
    if (i < 256 * 128) {                          // W0 [128][256] -> w0t [256][128]
        int n = i / 128, k = i - n * 128;
        w0t[i] = f2bf(W0[(size_t)k * 256 + n]);
        return;
    }
    i -= 256 * 128;
    if (i < 256 * 256) {                          // W1 [256][256] -> w1t [256][256]
        int n = i / 256, k = i - n * 256;
        w1t[i] = f2bf(W1[(size_t)k * 256 + n]);
        return;
    }
    i -= 256 * 256;
    if (i < 32 * 256) {                           // W2 [256][32] -> w2t [32][256]
        int n = i / 256, k = i - n * 256;
        w2t[i] = f2bf(W2[(size_t)k * 32 + n]);
    }
}

// ---------------- scan + gstart (fused, single block) ----------------

__global__ void scan_kernel(const int* __restrict__ deg, int* __restrict__ rowptr, int n,
                            const int* __restrict__ batch, int* __restrict__ gstart,
                            int N, int G) {
    const int tid = threadIdx.x;
    if (tid <= G) {
        int lo = 0, hi = N;
        while (lo < hi) { int mid = (lo + hi) >> 1; if (batch[mid] < tid) lo = mid + 1; else hi = mid; }
        gstart[tid] = lo;
    }
    __shared__ int partial[1024];
    const int chunk = (n + 1023) / 1024;
    const int start = min(tid * chunk, n);
    const int end = min(start + chunk, n);
    int s = 0;
    for (int i = start; i < end; i++) s += deg[i];
    partial[tid] = s;
    __syncthreads();
    for (int o = 1; o < 1024; o <<= 1) {
        int v = (tid >= o) ? partial[tid - o] : 0;
        __syncthreads();
        partial[tid] += v;
        __syncthreads();
    }
    int run = (tid == 0) ? 0 : partial[tid - 1];
    for (int i = start; i < end; i++) { rowptr[i] = run; run += deg[i]; }
    if (tid == 0) rowptr[n] = partial[1023];
}

// ---------------- mega0: gemm0(+al) ∥ 4-bin scatter ----------------
// gemm blocks first (MFMA-bound); scatter bins follow in block-ID order
// (~sequential: blocks/bin >> resident blocks) -> R6 write locality (1.6 MB
// window/bin). Bins write disjoint dst ranges -> order-independent. After
// all bins: rowptr[n] = END of segment n (shifted convention).

__global__ __launch_bounds__(256)
void mega0_kernel(const unsigned short* __restrict__ A, const unsigned short* __restrict__ Bt,
                  unsigned short* __restrict__ Cc,
                  const float* __restrict__ a_src, const float* __restrict__ a_dst,
                  float* __restrict__ als, float* __restrict__ ald, int M, int K,
                  const int* __restrict__ src, const int* __restrict__ dst,
                  int* __restrict__ rowptr, int* __restrict__ col, int E, int N,
                  int GEMM_BLKS, int SCAT_BLKS) {
    __shared__ __attribute__((aligned(16))) unsigned short Ab[128 * 64];
    __shared__ __attribute__((aligned(16))) unsigned short Bb[128 * 64];
    const int bid = blockIdx.x;
    if (bid < GEMM_BLKS) {
        gemm_core<128, 128, 64, 64, 8>(Ab, Bb, A, Bt, Cc, a_src, a_dst, als, ald,
                                       M, 256, K, bid & 1, bid >> 1);
        return;
    }
    const int sb = bid - GEMM_BLKS;
    const int bin = sb / SCAT_BLKS;
    const int i = (sb - bin * SCAT_BLKS) * 256 + threadIdx.x;
    const int lo = (int)((long long)N * bin / 4);
    const int hi = (int)((long long)N * (bin + 1) / 4);
    int s, d;
    if (i < E) { d = dst[i]; s = src[i]; }
    else if (i < E + N) { d = i - E; s = d; }
    else return;
    if (d < lo || d >= hi) return;
    int pos = atomicAdd(&rowptr[d], 1);
    col[pos] = s;
}

// ---------------- standalone GEMM (+al) for layers 1, 2 ----------------

template <int BM, int BN, int WM, int WN, int H>
__global__ __launch_bounds__(256)
void gemm_bf16_al(const unsigned short* __restrict__ A, const unsigned short* __restrict__ Bt,
                  unsigned short* __restrict__ Cc,
                  const float* __restrict__ a_src, const float* __restrict__ a_dst,
                  float* __restrict__ als, float* __restrict__ ald,
                  int M, int Nn, int K) {
    __shared__ __attribute__((aligned(16))) unsigned short Ab[BM * 64];
    __shared__ __attribute__((aligned(16))) unsigned short Bb[BN * 64];
    gemm_core<BM, BN, WM, WN, H>(Ab, Bb, A, Bt, Cc, a_src, a_dst, als, ald,
                                 M, Nn, K, blockIdx.x, blockIdx.y);
}

// ---------------- H=8 aggregate: wave-per-node, fused edge weights ----------------

__global__ __launch_bounds__(256)
void gat_agg_w8(const unsigned short* __restrict__ hfeat,
                const float* __restrict__ als, const float* __restrict__ ald,
                const int* __restrict__ rowptr,           // shifted: rowptr[n] = END
                const int* __restrict__ col,
                const float* __restrict__ bias,
                unsigned short* __restrict__ outH,
                int N) {
    constexpr int CAP = 128;
    const int wid = threadIdx.x >> 6;
    const int lane = threadIdx.x & 63;
    const int n = blockIdx.x * 4 + wid;
    __shared__ float se_all[4][CAP * 8];
    __shared__ int scol_all[4][CAP];
    if (n >= N) return;
    float* se = se_all[wid];
    int* scol = scol_all[wid];

    const int r0 = (n == 0) ? 0 : rowptr[n - 1];
    const int deg = rowptr[n] - r0;
    const int dcap = min(deg, CAP);

    // stage col -> LDS (coalesced; same wave reads below, no barrier needed)
    for (int j = lane; j < dcap; j += 64) scol[j] = col[r0 + j];

    // ---- pass A: fused weights; slot = lane>>3 (edge), h = lane&7 (head) ----
    const int slot = lane >> 3, h = lane & 7;
    const float aldh = ald[(size_t)n * 8 + h];
    float psum = 0.f;
    for (int j = 0; j < deg; j += 8) {
        int e = j + slot;
        if (e < deg) {
            int s = (e < dcap) ? scol[e] : col[r0 + e];
            float ev = als[(size_t)s * 8 + h] + aldh;
            ev = LRELU(ev);
            float w = __expf(ev);
            psum += w;
            if (e < CAP) se[e * 8 + h] = w;
        }
    }
#pragma unroll
    for (int m = 8; m < 64; m <<= 1) psum += __shfl_xor(psum, m);
    const int q = lane >> 3;                 // this lane's head in pass B
    const float sinv = 1.0f / __shfl(psum, q);
    const float aldq = ald[(size_t)n * 8 + q];

    // ---- pass B: 4-deep gather ----
    const int cb = lane * 4;
    float a0 = 0.f, a1 = 0.f, a2 = 0.f, a3 = 0.f;
    int j = 0;
    for (; j + 3 < dcap; j += 4) {
        int s0 = __builtin_amdgcn_readfirstlane(scol[j]);
        int s1 = __builtin_amdgcn_readfirstlane(scol[j + 1]);
        int s2 = __builtin_amdgcn_readfirstlane(scol[j + 2]);
        int s3 = __builtin_amdgcn_readfirstlane(scol[j + 3]);
        ushort4v v0 = *(const ushort4v*)(hfeat + (size_t)s0 * 256 + cb);
        ushort4v v1 = *(const ushort4v*)(hfeat + (size_t)s1 * 256 + cb);
        ushort4v v2 = *(const ushort4v*)(hfeat + (size_t)s2 * 256 + cb);
        ushort4v v3 = *(const ushort4v*)(hfeat + (size_t)s3 * 256 + cb);
        float w0 = se[j * 8 + q];
        float w1 = se[j * 8 + 8 + q];
        float w2 = se[j * 8 + 16 + q];
        float w3 = se[j * 8 + 24 + q];
        a0 += bf2f(v0[0]) * w0; a1 += bf2f(v0[1]) * w0; a2 += bf2f(v0[2]) * w0; a3 += bf2f(v0[3]) * w0;
        a0 += bf2f(v1[0]) * w1; a1 += bf2f(v1[1]) * w1; a2 += bf2f(v1[2]) * w1; a3 += bf2f(v1[3]) * w1;
        a0 += bf2f(v2[0]) * w2; a1 += bf2f(v2[1]) * w2; a2 += bf2f(v2[2]) * w2; a3 += bf2f(v2[3]) * w2;
        a0 += bf2f(v3[0]) * w3; a1 += bf2f(v3[1]) * w3; a2 += bf2f(v3[2]) * w3; a3 += bf2f(v3[3]) * w3;
    }
    for (; j < dcap; j++) {
        int s0 = __builtin_amdgcn_readfirstlane(scol[j]);
        ushort4v v0 = *(const ushort4v*)(hfeat + (size_t)s0 * 256 + cb);
        float w0 = se[j * 8 + q];
        a0 += bf2f(v0[0]) * w0; a1 += bf2f(v0[1]) * w0; a2 += bf2f(v0[2]) * w0; a3 += bf2f(v0[3]) * w0;
    }
    for (; j < deg; j++) {                   // deg > CAP fallback (essentially never)
        int s0 = col[r0 + j];
        float ev = als[(size_t)s0 * 8 + q] + aldq;
        ev = LRELU(ev);
        float w0 = __expf(ev);
        ushort4v v0 = *(const ushort4v*)(hfeat + (size_t)s0 * 256 + cb);
        a0 += bf2f(v0[0]) * w0; a1 += bf2f(v0[1]) * w0; a2 += bf2f(v0[2]) * w0; a3 += bf2f(v0[3]) * w0;
    }

    // ---- epilogue: normalize + bias + relu + bf16 store ----
    float4 b4 = *(const float4*)&bias[cb];
    float o0 = fmaxf(a0 * sinv + b4.x, 0.f);
    float o1 = fmaxf(a1 * sinv + b4.y, 0.f);
    float o2 = fmaxf(a2 * sinv + b4.z, 0.f);
    float o3 = fmaxf(a3 * sinv + b4.w, 0.f);
    const size_t ob = (size_t)n * 256 + cb;
    *(ushort4v*)&outH[ob] = (ushort4v){f2bf(o0), f2bf(o1), f2bf(o2), f2bf(o3)};
}

// ---------------- H=1 aggregate: wave-per-node, fused weights ----------------

__global__ __launch_bounds__(256)
void gat_agg_h1w(const unsigned short* __restrict__ hfeat,
                 const float* __restrict__ als, const float* __restrict__ ald,
                 const int* __restrict__ rowptr, const int* __restrict__ col,
                 const float* __restrict__ bias, float* __restrict__ out, int N) {
    constexpr int CAP = 256;
    const int wid = threadIdx.x >> 6;
    const int lane = threadIdx.x & 63;
    const int n = blockIdx.x * 4 + wid;
    __shared__ float sw_all[4][CAP];
    __shared__ int scol_all[4][CAP];
    if (n >= N) return;
    float* sw = sw_all[wid];
    int* scol = scol_all[wid];

    const int r0 = (n == 0) ? 0 : rowptr[n - 1];
    const int deg = rowptr[n] - r0;
    const int dcap = min(deg, CAP);
    const float aldn = ald[n];

    float lsum = 0.f;
    for (int idx = lane; idx < deg; idx += 64) {
        int s = col[r0 + idx];
        float ev = als[s] + aldn;
        ev = LRELU(ev);
        float w = __expf(ev);
        if (idx < CAP) { sw[idx] = w; scol[idx] = s; }
        lsum += w;
    }
#pragma unroll
    for (int m = 1; m < 64; m <<= 1) lsum += __shfl_xor(lsum, m);
    const float sinv = 1.0f / lsum;

    const int slot = lane >> 3, ch = lane & 7;
    float a0 = 0.f, a1 = 0.f, a2 = 0.f, a3 = 0.f;
    for (int j = 0; j < dcap; j += 8) {
        int e = j + slot;
        int ec = min(e, dcap - 1);
        int s = scol[ec];
        float w = (e < dcap) ? sw[ec] : 0.f;
        ushort4v v = *(const ushort4v*)(hfeat + (size_t)s * 32 + ch * 4);
        a0 += bf2f(v[0]) * w; a1 += bf2f(v[1]) * w;
        a2 += bf2f(v[2]) * w; a3 += bf2f(v[3]) * w;
    }
    for (int j = CAP; j < deg; j += 8) {     // deg > CAP fallback
        int e = j + slot;
        int ec = min(e, deg - 1);
        int s = col[r0 + ec];
        float w = 0.f;
        if (e < deg) {
            float ev = als[s] + aldn;
            ev = LRELU(ev);
            w = __expf(ev);
        }
        ushort4v v = *(const ushort4v*)(hfeat + (size_t)s * 32 + ch * 4);
        a0 += bf2f(v[0]) * w; a1 += bf2f(v[1]) * w;
        a2 += bf2f(v[2]) * w; a3 += bf2f(v[3]) * w;
    }
#pragma unroll
    for (int m = 8; m < 64; m <<= 1) {
        a0 += __shfl_xor(a0, m);
        a1 += __shfl_xor(a1, m);
        a2 += __shfl_xor(a2, m);
        a3 += __shfl_xor(a3, m);
    }
    if (slot == 0) {
        float4 b4 = *(const float4*)&bias[ch * 4];
        float4 o;
        o.x = a0 * sinv + b4.x;
        o.y = a1 * sinv + b4.y;
        o.z = a2 * sinv + b4.z;
        o.w = a3 * sinv + b4.w;
        *(float4*)&out[(size_t)n * 32 + ch * 4] = o;
    }
}

// ---------------- fused pool + head (sorted batch, no atomics) ----------------

__global__ __launch_bounds__(256)
void pool_final_kernel(const float* __restrict__ h, const int* __restrict__ gstart,
                       const float* __restrict__ lin_w, const float* __restrict__ lin_b,
                       float* __restrict__ out) {
    const int g = blockIdx.x;
    const int tid = threadIdx.x;
    const int n0 = gstart[g], n1 = gstart[g + 1];
    const int r = tid >> 5, c = tid & 31;
    __shared__ float pp[4][32];
    __shared__ float pm[32];
    float acc = 0.f;
    for (int n = n0 + r; n < n1; n += 8) acc += h[(size_t)n * 32 + c];
    acc += __shfl_xor(acc, 32);
    if ((tid & 63) < 32) pp[tid >> 6][c] = acc;
    __syncthreads();
    if (tid < 32) {
        float s = pp[0][tid] + pp[1][tid] + pp[2][tid] + pp[3][tid];
        pm[tid] = s / fmaxf((float)(n1 - n0), 1.f);
    }
    __syncthreads();
    if (tid < 64) {
        float a = lin_b[tid];
#pragma unroll 8
        for (int cc = 0; cc < 32; cc++) a += pm[cc] * lin_w[cc * 64 + tid];
        out[(size_t)g * 64 + tid] = a;
    }
}

// ---------------- launch ----------------

extern "C" void kernel_launch(void* const* d_in, const int* in_sizes, int n_in,
                              void* d_out, int out_size, void* d_ws, size_t ws_size,
                              hipStream_t stream) {
    const float* x     = (const float*)d_in[0];
    const int*   ei    = (const int*)d_in[1];
    const int*   batch = (const int*)d_in[2];
    const float* W0    = (const float*)d_in[3];
    const float* a_s0  = (const float*)d_in[4];
    const float* a_d0  = (const float*)d_in[5];
    const float* b0    = (const float*)d_in[6];
    const float* W1    = (const float*)d_in[7];
    const float* a_s1  = (const float*)d_in[8];
    const float* a_d1  = (const float*)d_in[9];
    const float* b1    = (const float*)d_in[10];
    const float* W2    = (const float*)d_in[11];
    const float* a_s2  = (const float*)d_in[12];
    const float* a_d2  = (const float*)d_in[13];
    const float* b2    = (const float*)d_in[14];
    const float* lin_w = (const float*)d_in[15];
    const float* lin_b = (const float*)d_in[16];

    const int N = in_sizes[0] / 128;   // 50000
    const int E = in_sizes[1] / 2;     // 1600000
    const int G = 256;
    const int Etot = E + N;
    const int* src = ei;
    const int* dst = ei + E;

    char* w = (char*)d_ws;
    size_t off = 0;
    auto alloc = [&](size_t bytes) -> void* {
        void* p = (void*)(w + off);
        off += (bytes + 255) & ~(size_t)255;
        return p;
    };
    int* deg    = (int*)alloc((size_t)N * 4);
    int* rowptr = (int*)alloc((size_t)(N + 1) * 4);
    int* colA   = (int*)alloc((size_t)Etot * 4);
    int* gstart = (int*)alloc((size_t)(G + 1) * 4);
    float* als  = (float*)alloc((size_t)N * 8 * 4);
    float* ald  = (float*)alloc((size_t)N * 8 * 4);
    unsigned short* hb  = (unsigned short*)alloc((size_t)N * 256 * 2);   // GEMM output
    unsigned short* g0  = (unsigned short*)alloc((size_t)N * 256 * 2);   // agg output
    float* out2 = (float*)alloc((size_t)N * 32 * 4);
    unsigned short* w0t = (unsigned short*)alloc((size_t)256 * 128 * 2); // W0^T bf16
    unsigned short* w1t = (unsigned short*)alloc((size_t)256 * 256 * 2);
    unsigned short* w2t = (unsigned short*)alloc((size_t)32 * 256 * 2);
    unsigned short* xb = g0;                        // x bf16, aliased (dead before agg0 writes g0)

    hipMemsetAsync(deg, 0, (size_t)N * 4, stream);

    // deg ∥ prep (independent; block-range fused)
    {
        const int DEG_BLKS = (Etot + 255) / 256;
        long long prep_elems = (long long)N * 128 + 256 * 128 + 256 * 256 + 32 * 256;
        const int PREP_BLKS = (int)((prep_elems + 255) / 256);
        deg_prep_kernel<<<DEG_BLKS + PREP_BLKS, 256, 0, stream>>>(
            dst, deg, E, N, x, W0, W1, W2, xb, w0t, w1t, w2t, DEG_BLKS);
    }

    // scan + gstart
    scan_kernel<<<1, 1024, 0, stream>>>(deg, rowptr, N, batch, gstart, N, G);

    const int MB = (N + 127) / 128;

    // gemm0(+al) ∥ 4-bin scatter (independent; agg0 needs both)
    {
        const int GEMM_BLKS = 2 * MB;
        const int SCAT_BLKS = (Etot + 255) / 256;
        mega0_kernel<<<GEMM_BLKS + 4 * SCAT_BLKS, 256, 0, stream>>>(
            xb, w0t, hb, a_s0, a_d0, als, ald, N, 128,
            src, dst, rowptr, colA, E, N, GEMM_BLKS, SCAT_BLKS);
    }
    gat_agg_w8<<<(N + 3) / 4, 256, 0, stream>>>(hb, als, ald, rowptr, colA, b0, g0, N);

    // layer 1: K=256
    gemm_bf16_al<128, 128, 64, 64, 8><<<dim3(2, MB), 256, 0, stream>>>(
        g0, w1t, hb, a_s1, a_d1, als, ald, N, 256, 256);
    gat_agg_w8<<<(N + 3) / 4, 256, 0, stream>>>(hb, als, ald, rowptr, colA, b1, g0, N);

    // layer 2: heads=1, C=32, K=256
    gemm_bf16_al<128, 32, 32, 32, 1><<<dim3(1, MB), 256, 0, stream>>>(
        g0, w2t, hb, a_s2, a_d2, als, ald, N, 32, 256);
    gat_agg_h1w<<<(N + 3) / 4, 256, 0, stream>>>(hb, als, ald, rowptr, colA, b2, out2, N);

    // fused pool + head
    pool_final_kernel<<<G, 256, 0, stream>>>(out2, gstart, lin_w, lin_b, (float*)d_out);
}